// Round 5
// baseline (2843.794 us; speedup 1.0000x reference)
//
#include <hip/hip_runtime.h>
#include <math.h>

#define NN_ 1024
#define DOUT_ 2112
#define NOUT_ 384
#define MT2_ 16
#define NT2_ 64

// ---------------- K1: yraw[1024][1152] = in1 @ [wq|wkv|wqp|wkvp] + bias ----------------
__global__ __launch_bounds__(256) void k_gemm1(
    const float* __restrict__ in1,
    const float* __restrict__ wq, const float* __restrict__ bq,
    const float* __restrict__ wkv, const float* __restrict__ bkv,
    const float* __restrict__ wqp, const float* __restrict__ bqp,
    const float* __restrict__ wkvp, const float* __restrict__ bkvp,
    float* __restrict__ yraw)
{
    __shared__ float a_l[64 * 36];
    __shared__ float b_l[32 * 68];
    const int t = threadIdx.x;
    const int m0 = blockIdx.x * 64, j0 = blockIdx.y * 64;
    const int tx = t & 15, ty = t >> 4;
    float acc[4][4] = {};
    for (int k0 = 0; k0 < 384; k0 += 32) {
        #pragma unroll
        for (int e = 0; e < 2; ++e) {
            int idx = t + 256 * e;
            int r = idx >> 3, c4 = (idx & 7) * 4;
            *(float4*)&a_l[r * 36 + c4] = *(const float4*)&in1[(size_t)(m0 + r) * 384 + k0 + c4];
        }
        #pragma unroll
        for (int e = 0; e < 2; ++e) {
            int idx = t + 256 * e;
            int r = idx >> 4, c4 = (idx & 15) * 4;
            int j = j0 + c4;
            const float* w; int ncol, jj;
            if (j < 192)      { w = wq;   ncol = 192; jj = j; }
            else if (j < 576) { w = wkv;  ncol = 384; jj = j - 192; }
            else if (j < 720) { w = wqp;  ncol = 144; jj = j - 576; }
            else              { w = wkvp; ncol = 432; jj = j - 720; }
            *(float4*)&b_l[r * 68 + c4] = *(const float4*)&w[(size_t)(k0 + r) * ncol + jj];
        }
        __syncthreads();
        #pragma unroll 8
        for (int k = 0; k < 32; ++k) {
            float4 bv = *(const float4*)&b_l[k * 68 + tx * 4];
            #pragma unroll
            for (int i = 0; i < 4; ++i) {
                float av = a_l[(ty * 4 + i) * 36 + k];
                acc[i][0] += av * bv.x; acc[i][1] += av * bv.y;
                acc[i][2] += av * bv.z; acc[i][3] += av * bv.w;
            }
        }
        __syncthreads();
    }
    int j = j0 + tx * 4;
    float4 bias;
    {
        const float* b; int jj;
        if (j < 192)      { b = bq;   jj = j; }
        else if (j < 576) { b = bkv;  jj = j - 192; }
        else if (j < 720) { b = bqp;  jj = j - 576; }
        else              { b = bkvp; jj = j - 720; }
        bias = *(const float4*)&b[jj];
    }
    #pragma unroll
    for (int i = 0; i < 4; ++i) {
        float4 o;
        o.x = acc[i][0] + bias.x; o.y = acc[i][1] + bias.y;
        o.z = acc[i][2] + bias.z; o.w = acc[i][3] + bias.w;
        *(float4*)&yraw[(size_t)(m0 + ty * 4 + i) * 1152 + j] = o;
    }
}

// ---------------- K2: rotations + packing ----------------
// kpack[n][352]: [0:192 ks(h*16+s)] [192:336 kp(a*48+h*4+p)] [336:348 sk(h)]
// vpack[n][480]: [0:192 vs(h*16+s)] [192:480 vp(a*96+h*8+p)]
__global__ __launch_bounds__(256) void k_rot(
    const float* __restrict__ yraw, const float* __restrict__ rotm, const float* __restrict__ trans,
    float* __restrict__ qp_arr, float* __restrict__ kpack, float* __restrict__ vpack,
    float* __restrict__ sq_arr)
{
    __shared__ float rt_l[4][12];
    const int t = threadIdx.x;
    const int n0 = blockIdx.x * 4;
    if (t < 48) {
        int n_ = t / 12, i = t % 12;
        rt_l[n_][i] = (i < 9) ? rotm[(n0 + n_) * 9 + i] : trans[(n0 + n_) * 3 + (i - 9)];
    }
    __syncthreads();
    const int n_ = t >> 6, l = t & 63;
    const int n = n0 + n_;
    const float* y = yraw + (size_t)n * 1152;
    const float* R = rt_l[n_];
    #pragma unroll
    for (int jj = 0; jj < 9; ++jj) {
        int o = l + 64 * jj;
        if (o < 144) {
            int a = o / 48, kk = o % 48;
            float v = R[9 + a] + R[a*3+0] * y[576 + kk] + R[a*3+1] * y[576 + 48 + kk] + R[a*3+2] * y[576 + 96 + kk];
            qp_arr[(size_t)n * 144 + o] = v;
        } else if (o < 288) {
            int o2 = o - 144;
            int a = o2 / 48, r2 = o2 % 48;
            int kk = (r2 >> 2) * 12 + (r2 & 3);
            float v = R[9 + a] + R[a*3+0] * y[720 + kk] + R[a*3+1] * y[720 + 144 + kk] + R[a*3+2] * y[720 + 288 + kk];
            kpack[(size_t)n * 352 + 192 + o2] = v;
        } else {
            int o3 = o - 288;
            int a = o3 / 96, r2 = o3 % 96;
            int kk = (r2 >> 3) * 12 + 4 + (r2 & 7);
            float v = R[9 + a] + R[a*3+0] * y[720 + kk] + R[a*3+1] * y[720 + 144 + kk] + R[a*3+2] * y[720 + 288 + kk];
            vpack[(size_t)n * 480 + 192 + o3] = v;
        }
    }
    #pragma unroll
    for (int jj = 0; jj < 3; ++jj) {
        int o = l + 64 * jj;  // 0..191
        int h = o >> 4, r2 = o & 15;
        kpack[(size_t)n * 352 + o] = y[192 + h * 32 + r2];
        vpack[(size_t)n * 480 + o] = y[192 + h * 32 + 16 + r2];
    }
    if (l < 24) {
        int which = l / 12, h = l % 12;
        int base = (which == 0) ? 576 : 720;
        int stride = (which == 0) ? 48 : 144;
        float s = 0.f;
        #pragma unroll
        for (int a = 0; a < 3; ++a) {
            #pragma unroll
            for (int p = 0; p < 4; ++p) {
                int kk = (which == 0) ? (h * 4 + p) : (h * 12 + p);
                float v = R[9 + a] + R[a*3+0] * y[base + kk] + R[a*3+1] * y[base + stride + kk] + R[a*3+2] * y[base + 2 * stride + kk];
                s += v * v;
            }
        }
        if (which == 0) sq_arr[(size_t)n * 12 + h] = s;
        else            kpack[(size_t)n * 352 + 336 + h] = s;
    }
}

// ---------------- K3: fused flash IPA, 2 query rows per block, 256 threads ----------------
__global__ __launch_bounds__(256, 4) void k_attn4(
    const float* __restrict__ x2d, const float* __restrict__ mask,
    const float* __restrict__ w2d, const float* __restrict__ b2d, const float* __restrict__ tpw,
    const float* __restrict__ yraw, const float* __restrict__ qp_arr,
    const float* __restrict__ kpack, const float* __restrict__ vpack,
    const float* __restrict__ sq_arr, const float* __restrict__ rotm,
    const float* __restrict__ trans,
    float* __restrict__ fin)
{
    __shared__ float x_l[2][MT2_][132];   // 16.9 KB
    __shared__ float w2_l[12][128];       // 6.1 KB
    __shared__ float tl[2][12][20];       // p values
    __shared__ float at2_l[2][MT2_][13];
    __shared__ float qs_l[2][192];
    __shared__ float qp_l[2][144];
    __shared__ float sq_l[2][12];
    __shared__ float rt_l[2][12];
    __shared__ float pw_l[12], b2_l[12];
    __shared__ float maskn_l[2];
    __shared__ float rmax_l[2][12], rsum_l[2][12], alph_l[2][12];
    __shared__ float pg_l[2][288];

    const int t = threadIdx.x;
    const int n0 = blockIdx.x * 2;

    // thread mappings
    const int sn = t >> 7;            // staging + res2d: n (0..1)
    const int sm = (t >> 3) & 15;     // staging: m
    const int k8 = t & 7;             // staging: c-octant (16 c)
    const int hx = t >> 4;            // P2: h (active < 12)
    const int m2 = t & 15;            // P2: m
    const int cc = t & 127;           // res2d: c
    const int jF = 2 * t;             // resF: j pair (t < 240)
    const int hF = (jF < 192) ? (jF >> 4) : (((jF - 192) % 96) >> 3);

    float accR[12];
    #pragma unroll
    for (int e = 0; e < 12; ++e) accR[e] = 0.f;
    float accF[4] = {0.f, 0.f, 0.f, 0.f};
    float4 xpf[4];

    // ---- prologue ----
    for (int i = t; i < 1536; i += 256) { int c = i / 12, h = i % 12; w2_l[h][c] = w2d[i]; }
    if (t < 192) { qs_l[0][t] = yraw[(size_t)n0 * 1152 + t]; qs_l[1][t] = yraw[(size_t)(n0 + 1) * 1152 + t]; }
    if (t < 144) { qp_l[0][t] = qp_arr[(size_t)n0 * 144 + t]; qp_l[1][t] = qp_arr[(size_t)(n0 + 1) * 144 + t]; }
    if (t < 24)  { sq_l[t / 12][t % 12] = sq_arr[(size_t)(n0 + t / 12) * 12 + (t % 12)]; }
    if (t >= 32 && t < 56) {
        int i = t - 32, nl = i / 12, r = i % 12;
        rt_l[nl][r] = (r < 9) ? rotm[(n0 + nl) * 9 + r] : trans[(n0 + nl) * 3 + (r - 9)];
    }
    if (t >= 64 && t < 76)  pw_l[t - 64] = 0.13608276348795434f * log1pf(__expf(tpw[t - 64]));
    if (t >= 96 && t < 108) b2_l[t - 96] = b2d[t - 96];
    if (t >= 128 && t < 130) maskn_l[t - 128] = mask[n0 + (t - 128)];
    if (t >= 160 && t < 184) { int i = t - 160; rmax_l[i / 12][i % 12] = -3.0e38f; }
    if (t >= 192 && t < 216) { int i = t - 192; rsum_l[i / 12][i % 12] = 0.f; }

    // initial x prefetch (tile 0)
    #pragma unroll
    for (int f = 0; f < 4; ++f)
        xpf[f] = *(const float4*)&x2d[((size_t)(n0 + sn) * NN_ + sm) * 128 + k8 * 16 + f * 4];
    __syncthreads();

    for (int mt = 0; mt < NT2_; ++mt) {
        const int m0 = mt * MT2_;
        // ===== P1: commit x prefetch to LDS + att2d partial dots =====
        #pragma unroll
        for (int f = 0; f < 4; ++f)
            *(float4*)&x_l[sn][sm][k8 * 16 + f * 4] = xpf[f];
        {
            float at2[12];
            #pragma unroll
            for (int h = 0; h < 12; ++h) {
                float s = 0.f;
                #pragma unroll
                for (int f = 0; f < 4; ++f) {
                    float4 wv = *(const float4*)&w2_l[h][k8 * 16 + f * 4];
                    s += xpf[f].x * wv.x + xpf[f].y * wv.y + xpf[f].z * wv.z + xpf[f].w * wv.w;
                }
                at2[h] = s;
            }
            #pragma unroll
            for (int d = 1; d <= 4; d <<= 1) {
                #pragma unroll
                for (int h = 0; h < 12; ++h) at2[h] += __shfl_xor(at2[h], d);
            }
            if (k8 == 0) {
                #pragma unroll
                for (int h = 0; h < 12; ++h) at2_l[sn][sm][h] = at2[h];
            }
        }
        __syncthreads();

        // ===== P2: logits + online softmax; all threads prefetch next x =====
        {
            int m1 = (mt + 1 == NT2_) ? 0 : (m0 + MT2_);
            #pragma unroll
            for (int f = 0; f < 4; ++f)
                xpf[f] = *(const float4*)&x2d[((size_t)(n0 + sn) * NN_ + m1 + sm) * 128 + k8 * 16 + f * 4];
        }
        if (hx < 12) {
            const int h = hx;
            const float* kr = kpack + (size_t)(m0 + m2) * 352;
            float4 ksA = *(const float4*)&kr[h * 16 + 0];
            float4 ksB = *(const float4*)&kr[h * 16 + 4];
            float4 ksC = *(const float4*)&kr[h * 16 + 8];
            float4 ksD = *(const float4*)&kr[h * 16 + 12];
            float4 kpA = *(const float4*)&kr[192 + h * 4];
            float4 kpB = *(const float4*)&kr[192 + 48 + h * 4];
            float4 kpC = *(const float4*)&kr[192 + 96 + h * 4];
            float skm = kr[336 + h];
            float mkm = mask[m0 + m2];
            float pwh = pw_l[h];
            #pragma unroll
            for (int nn = 0; nn < 2; ++nn) {
                const float4* qsn = (const float4*)&qs_l[nn][h * 16];
                float dqs = qsn[0].x*ksA.x + qsn[0].y*ksA.y + qsn[0].z*ksA.z + qsn[0].w*ksA.w
                          + qsn[1].x*ksB.x + qsn[1].y*ksB.y + qsn[1].z*ksB.z + qsn[1].w*ksB.w
                          + qsn[2].x*ksC.x + qsn[2].y*ksC.y + qsn[2].z*ksC.z + qsn[2].w*ksC.w
                          + qsn[3].x*ksD.x + qsn[3].y*ksD.y + qsn[3].z*ksD.z + qsn[3].w*ksD.w;
                float4 qA = *(const float4*)&qp_l[nn][h * 4];
                float4 qB = *(const float4*)&qp_l[nn][48 + h * 4];
                float4 qC = *(const float4*)&qp_l[nn][96 + h * 4];
                float qk = qA.x*kpA.x + qA.y*kpA.y + qA.z*kpA.z + qA.w*kpA.w
                         + qB.x*kpB.x + qB.y*kpB.y + qB.z*kpB.z + qB.w*kpB.w
                         + qC.x*kpC.x + qC.y*kpC.y + qC.z*kpC.z + qC.w*kpC.w;
                float lg = 0.14433756729740643f * dqs
                         + pwh * qk - 0.5f * pwh * (sq_l[nn][h] + skm)
                         + 0.57735026918962576f * (at2_l[nn][m2][h] + b2_l[h])
                         - 100000.0f * (1.0f - maskn_l[nn] * mkm);
                float tm = lg;
                tm = fmaxf(tm, __shfl_xor(tm, 1));
                tm = fmaxf(tm, __shfl_xor(tm, 2));
                tm = fmaxf(tm, __shfl_xor(tm, 4));
                tm = fmaxf(tm, __shfl_xor(tm, 8));
                float om = rmax_l[nn][h];
                float nm = fmaxf(om, tm);
                float p = __expf(lg - nm);
                tl[nn][h][m2] = p;
                float ps = p;
                ps += __shfl_xor(ps, 1);
                ps += __shfl_xor(ps, 2);
                ps += __shfl_xor(ps, 4);
                ps += __shfl_xor(ps, 8);
                if (m2 == 0) {
                    float al = __expf(om - nm);
                    rmax_l[nn][h] = nm;
                    alph_l[nn][h] = al;
                    rsum_l[nn][h] = rsum_l[nn][h] * al + ps;
                }
            }
        }
        __syncthreads();

        // ===== P5: rescale + res2d (x from LDS, p broadcast) =====
        {
            #pragma unroll
            for (int h = 0; h < 12; ++h) accR[h] *= alph_l[sn][h];
            #pragma unroll
            for (int mm = 0; mm < MT2_; mm += 4) {
                float x0  = x_l[sn][mm + 0][cc];
                float x1  = x_l[sn][mm + 1][cc];
                float x2v = x_l[sn][mm + 2][cc];
                float x3  = x_l[sn][mm + 3][cc];
                #pragma unroll
                for (int h = 0; h < 12; ++h) {
                    float4 pv = *(const float4*)&tl[sn][h][mm];
                    accR[h] += pv.x * x0 + pv.y * x1 + pv.z * x2v + pv.w * x3;
                }
            }
        }
        // ===== P6: resF (v from L2, shared by both n) =====
        if (t < 240) {
            float a0 = alph_l[0][hF], a1 = alph_l[1][hF];
            accF[0] *= a0; accF[1] *= a0; accF[2] *= a1; accF[3] *= a1;
            const float* vb = vpack + (size_t)m0 * 480 + jF;
            #pragma unroll
            for (int mm = 0; mm < MT2_; mm += 4) {
                float4 p0 = *(const float4*)&tl[0][hF][mm];
                float4 p1 = *(const float4*)&tl[1][hF][mm];
                float2 v0 = *(const float2*)&vb[(size_t)(mm + 0) * 480];
                float2 v1 = *(const float2*)&vb[(size_t)(mm + 1) * 480];
                float2 v2 = *(const float2*)&vb[(size_t)(mm + 2) * 480];
                float2 v3 = *(const float2*)&vb[(size_t)(mm + 3) * 480];
                accF[0] += p0.x * v0.x + p0.y * v1.x + p0.z * v2.x + p0.w * v3.x;
                accF[1] += p0.x * v0.y + p0.y * v1.y + p0.z * v2.y + p0.w * v3.y;
                accF[2] += p1.x * v0.x + p1.y * v1.x + p1.z * v2.x + p1.w * v3.x;
                accF[3] += p1.x * v0.y + p1.y * v1.y + p1.z * v2.y + p1.w * v3.y;
            }
        }
        __syncthreads();
    }

    // ================= epilogue =================
    {
        #pragma unroll
        for (int h = 0; h < 12; ++h) {
            float v = accR[h] / rsum_l[sn][h];
            fin[(size_t)(n0 + sn) * DOUT_ + 576 + (size_t)h * 128 + cc] = v;
        }
    }
    if (t < 240) {
        float i0 = 1.f / rsum_l[0][hF], i1 = 1.f / rsum_l[1][hF];
        float vA0 = accF[0] * i0, vA1 = accF[1] * i0;
        float vB0 = accF[2] * i1, vB1 = accF[3] * i1;
        if (jF < 192) {
            fin[(size_t)n0 * DOUT_ + jF] = vA0;       fin[(size_t)n0 * DOUT_ + jF + 1] = vA1;
            fin[(size_t)(n0 + 1) * DOUT_ + jF] = vB0; fin[(size_t)(n0 + 1) * DOUT_ + jF + 1] = vB1;
        } else {
            pg_l[0][jF - 192] = vA0; pg_l[0][jF - 191] = vA1;
            pg_l[1][jF - 192] = vB0; pg_l[1][jF - 191] = vB1;
        }
    }
    __syncthreads();
    if (t < 192) {
        const int n = t / 96, k = t % 96;
        const float* R = rt_l[n];
        float c0 = pg_l[n][k]       - R[9];
        float c1 = pg_l[n][96 + k]  - R[10];
        float c2 = pg_l[n][192 + k] - R[11];
        float r0 = R[0] * c0 + R[3] * c1 + R[6] * c2;
        float r1 = R[1] * c0 + R[4] * c1 + R[7] * c2;
        float r2 = R[2] * c0 + R[5] * c1 + R[8] * c2;
        size_t base = (size_t)(n0 + n) * DOUT_;
        fin[base + 192 + k] = r0;
        fin[base + 288 + k] = r1;
        fin[base + 384 + k] = r2;
        fin[base + 480 + k] = sqrtf(1e-8f + r0 * r0 + r1 * r1 + r2 * r2);
    }
}

// ---------------- K5: out partials, split-K over 4 chunks of 528 ----------------
__global__ __launch_bounds__(256) void k_out(
    const float* __restrict__ fin, const float* __restrict__ wo,
    float* __restrict__ pout)
{
    __shared__ float a_l[64 * 52];
    __shared__ float b_l[48 * 68];
    const int t = threadIdx.x;
    const int m0 = blockIdx.x * 64, n0 = blockIdx.y * 64, kc = blockIdx.z;
    const int tx = t & 15, ty = t >> 4;
    float acc[4][4] = {};
    for (int k0 = kc * 528; k0 < kc * 528 + 528; k0 += 48) {
        #pragma unroll
        for (int e = 0; e < 3; ++e) {
            int idx = t + 256 * e;
            int r = idx / 12, c4 = (idx % 12) * 4;
            *(float4*)&a_l[r * 52 + c4] = *(const float4*)&fin[(size_t)(m0 + r) * DOUT_ + k0 + c4];
        }
        #pragma unroll
        for (int e = 0; e < 3; ++e) {
            int idx = t + 256 * e;
            int r = idx >> 4, c4 = (idx & 15) * 4;
            *(float4*)&b_l[r * 68 + c4] = *(const float4*)&wo[(size_t)(k0 + r) * 384 + n0 + c4];
        }
        __syncthreads();
        #pragma unroll 4
        for (int k = 0; k < 48; ++k) {
            float4 bv = *(const float4*)&b_l[k * 68 + tx * 4];
            #pragma unroll
            for (int i = 0; i < 4; ++i) {
                float av = a_l[(ty * 4 + i) * 52 + k];
                acc[i][0] += av * bv.x; acc[i][1] += av * bv.y;
                acc[i][2] += av * bv.z; acc[i][3] += av * bv.w;
            }
        }
        __syncthreads();
    }
    float* pr = pout + (size_t)kc * 393216;
    #pragma unroll
    for (int i = 0; i < 4; ++i) {
        float4 o;
        o.x = acc[i][0]; o.y = acc[i][1]; o.z = acc[i][2]; o.w = acc[i][3];
        *(float4*)&pr[(size_t)(m0 + ty * 4 + i) * 384 + n0 + tx * 4] = o;
    }
}

// ---------------- K6: sum split-K partials + bias ----------------
__global__ __launch_bounds__(256) void k_fin(
    const float* __restrict__ pout, const float* __restrict__ bo, float* __restrict__ out)
{
    int idx = blockIdx.x * 256 + threadIdx.x;
    float4 a = *(const float4*)&pout[(size_t)idx * 4];
    float4 b = *(const float4*)&pout[393216 + (size_t)idx * 4];
    float4 c = *(const float4*)&pout[786432 + (size_t)idx * 4];
    float4 d = *(const float4*)&pout[1179648 + (size_t)idx * 4];
    float4 bias = *(const float4*)&bo[(idx % 96) * 4];
    float4 o;
    o.x = a.x + b.x + c.x + d.x + bias.x;
    o.y = a.y + b.y + c.y + d.y + bias.y;
    o.z = a.z + b.z + c.z + d.z + bias.z;
    o.w = a.w + b.w + c.w + d.w + bias.w;
    *(float4*)&out[(size_t)idx * 4] = o;
}

extern "C" void kernel_launch(void* const* d_in, const int* in_sizes, int n_in,
                              void* d_out, int out_size, void* d_ws, size_t ws_size,
                              hipStream_t stream) {
    const float* in1   = (const float*)d_in[0];
    const float* x2d   = (const float*)d_in[1];
    const float* mask  = (const float*)d_in[2];
    const float* rotm  = (const float*)d_in[3];
    const float* trans = (const float*)d_in[4];
    const float* wq    = (const float*)d_in[5];
    const float* bq    = (const float*)d_in[6];
    const float* wkv   = (const float*)d_in[7];
    const float* bkv   = (const float*)d_in[8];
    const float* wqp   = (const float*)d_in[9];
    const float* bqp   = (const float*)d_in[10];
    const float* wkvp  = (const float*)d_in[11];
    const float* bkvp  = (const float*)d_in[12];
    const float* w2d   = (const float*)d_in[13];
    const float* b2d   = (const float*)d_in[14];
    const float* tpw   = (const float*)d_in[15];
    const float* wo    = (const float*)d_in[16];
    const float* bo    = (const float*)d_in[17];
    float* out = (float*)d_out;

    float* ws = (float*)d_ws;
    float* yraw   = ws;                    // 1,179,648
    float* qp_arr = yraw + 1179648;        //   147,456
    float* kpack  = qp_arr + 147456;       //   360,448
    float* vpack  = kpack + 360448;        //   491,520
    float* sq_arr = vpack + 491520;        //    12,288
    float* fin    = sq_arr + 12288;        // 2,162,688
    float* pout   = fin + 2162688;         // 1,572,864

    hipLaunchKernelGGL(k_gemm1, dim3(16, 18), dim3(256), 0, stream,
        in1, wq, bq, wkv, bkv, wqp, bqp, wkvp, bkvp, yraw);
    hipLaunchKernelGGL(k_rot, dim3(256), dim3(256), 0, stream,
        yraw, rotm, trans, qp_arr, kpack, vpack, sq_arr);
    hipLaunchKernelGGL(k_attn4, dim3(512), dim3(256), 0, stream,
        x2d, mask, w2d, b2d, tpw, yraw, qp_arr, kpack, vpack, sq_arr, rotm, trans, fin);
    hipLaunchKernelGGL(k_out, dim3(16, 6, 4), dim3(256), 0, stream, fin, wo, pout);
    hipLaunchKernelGGL(k_fin, dim3(384), dim3(256), 0, stream, pout, bo, out);
}

// Round 6
// 935.531 us; speedup vs baseline: 3.0398x; 3.0398x over previous
//
#include <hip/hip_runtime.h>
#include <math.h>

#define NN_ 1024
#define DOUT_ 2112
#define NOUT_ 384
#define MT2_ 16
#define NT2_ 64

// ---------------- K1: yraw[1024][1152] = in1 @ [wq|wkv|wqp|wkvp] + bias ----------------
__global__ __launch_bounds__(256) void k_gemm1(
    const float* __restrict__ in1,
    const float* __restrict__ wq, const float* __restrict__ bq,
    const float* __restrict__ wkv, const float* __restrict__ bkv,
    const float* __restrict__ wqp, const float* __restrict__ bqp,
    const float* __restrict__ wkvp, const float* __restrict__ bkvp,
    float* __restrict__ yraw)
{
    __shared__ float a_l[64 * 36];
    __shared__ float b_l[32 * 68];
    const int t = threadIdx.x;
    const int m0 = blockIdx.x * 64, j0 = blockIdx.y * 64;
    const int tx = t & 15, ty = t >> 4;
    float acc[4][4] = {};
    for (int k0 = 0; k0 < 384; k0 += 32) {
        #pragma unroll
        for (int e = 0; e < 2; ++e) {
            int idx = t + 256 * e;
            int r = idx >> 3, c4 = (idx & 7) * 4;
            *(float4*)&a_l[r * 36 + c4] = *(const float4*)&in1[(size_t)(m0 + r) * 384 + k0 + c4];
        }
        #pragma unroll
        for (int e = 0; e < 2; ++e) {
            int idx = t + 256 * e;
            int r = idx >> 4, c4 = (idx & 15) * 4;
            int j = j0 + c4;
            const float* w; int ncol, jj;
            if (j < 192)      { w = wq;   ncol = 192; jj = j; }
            else if (j < 576) { w = wkv;  ncol = 384; jj = j - 192; }
            else if (j < 720) { w = wqp;  ncol = 144; jj = j - 576; }
            else              { w = wkvp; ncol = 432; jj = j - 720; }
            *(float4*)&b_l[r * 68 + c4] = *(const float4*)&w[(size_t)(k0 + r) * ncol + jj];
        }
        __syncthreads();
        #pragma unroll 8
        for (int k = 0; k < 32; ++k) {
            float4 bv = *(const float4*)&b_l[k * 68 + tx * 4];
            #pragma unroll
            for (int i = 0; i < 4; ++i) {
                float av = a_l[(ty * 4 + i) * 36 + k];
                acc[i][0] += av * bv.x; acc[i][1] += av * bv.y;
                acc[i][2] += av * bv.z; acc[i][3] += av * bv.w;
            }
        }
        __syncthreads();
    }
    int j = j0 + tx * 4;
    float4 bias;
    {
        const float* b; int jj;
        if (j < 192)      { b = bq;   jj = j; }
        else if (j < 576) { b = bkv;  jj = j - 192; }
        else if (j < 720) { b = bqp;  jj = j - 576; }
        else              { b = bkvp; jj = j - 720; }
        bias = *(const float4*)&b[jj];
    }
    #pragma unroll
    for (int i = 0; i < 4; ++i) {
        float4 o;
        o.x = acc[i][0] + bias.x; o.y = acc[i][1] + bias.y;
        o.z = acc[i][2] + bias.z; o.w = acc[i][3] + bias.w;
        *(float4*)&yraw[(size_t)(m0 + ty * 4 + i) * 1152 + j] = o;
    }
}

// ---------------- K2: rotations + packing ----------------
// kpack[n][352]: [0:192 ks(h*16+s)] [192:336 kp(a*48+h*4+p)] [336:348 sk(h)]
// vpack[n][480]: [0:192 vs(h*16+s)] [192:480 vp(a*96+h*8+p)]
__global__ __launch_bounds__(256) void k_rot(
    const float* __restrict__ yraw, const float* __restrict__ rotm, const float* __restrict__ trans,
    float* __restrict__ qp_arr, float* __restrict__ kpack, float* __restrict__ vpack,
    float* __restrict__ sq_arr)
{
    __shared__ float rt_l[4][12];
    const int t = threadIdx.x;
    const int n0 = blockIdx.x * 4;
    if (t < 48) {
        int n_ = t / 12, i = t % 12;
        rt_l[n_][i] = (i < 9) ? rotm[(n0 + n_) * 9 + i] : trans[(n0 + n_) * 3 + (i - 9)];
    }
    __syncthreads();
    const int n_ = t >> 6, l = t & 63;
    const int n = n0 + n_;
    const float* y = yraw + (size_t)n * 1152;
    const float* R = rt_l[n_];
    #pragma unroll
    for (int jj = 0; jj < 9; ++jj) {
        int o = l + 64 * jj;
        if (o < 144) {
            int a = o / 48, kk = o % 48;
            float v = R[9 + a] + R[a*3+0] * y[576 + kk] + R[a*3+1] * y[576 + 48 + kk] + R[a*3+2] * y[576 + 96 + kk];
            qp_arr[(size_t)n * 144 + o] = v;
        } else if (o < 288) {
            int o2 = o - 144;
            int a = o2 / 48, r2 = o2 % 48;
            int kk = (r2 >> 2) * 12 + (r2 & 3);
            float v = R[9 + a] + R[a*3+0] * y[720 + kk] + R[a*3+1] * y[720 + 144 + kk] + R[a*3+2] * y[720 + 288 + kk];
            kpack[(size_t)n * 352 + 192 + o2] = v;
        } else {
            int o3 = o - 288;
            int a = o3 / 96, r2 = o3 % 96;
            int kk = (r2 >> 3) * 12 + 4 + (r2 & 7);
            float v = R[9 + a] + R[a*3+0] * y[720 + kk] + R[a*3+1] * y[720 + 144 + kk] + R[a*3+2] * y[720 + 288 + kk];
            vpack[(size_t)n * 480 + 192 + o3] = v;
        }
    }
    #pragma unroll
    for (int jj = 0; jj < 3; ++jj) {
        int o = l + 64 * jj;  // 0..191
        int h = o >> 4, r2 = o & 15;
        kpack[(size_t)n * 352 + o] = y[192 + h * 32 + r2];
        vpack[(size_t)n * 480 + o] = y[192 + h * 32 + 16 + r2];
    }
    if (l < 24) {
        int which = l / 12, h = l % 12;
        int base = (which == 0) ? 576 : 720;
        int stride = (which == 0) ? 48 : 144;
        float s = 0.f;
        #pragma unroll
        for (int a = 0; a < 3; ++a) {
            #pragma unroll
            for (int p = 0; p < 4; ++p) {
                int kk = (which == 0) ? (h * 4 + p) : (h * 12 + p);
                float v = R[9 + a] + R[a*3+0] * y[base + kk] + R[a*3+1] * y[base + stride + kk] + R[a*3+2] * y[base + 2 * stride + kk];
                s += v * v;
            }
        }
        if (which == 0) sq_arr[(size_t)n * 12 + h] = s;
        else            kpack[(size_t)n * 352 + 336 + h] = s;
    }
}

// ---------------- K3: fused flash IPA, 2 query rows per block, 256 threads ----------------
// NOTE: plain __launch_bounds__(256). Adding a min-waves/occupancy hint (rounds 3-5)
// made the allocator cap at 64 VGPRs and spill ~10 GB to scratch. Without the hint
// the compiler allocates 120-144 VGPRs (rounds 1-2) and does not spill.
__global__ __launch_bounds__(256) void k_attn4(
    const float* __restrict__ x2d, const float* __restrict__ mask,
    const float* __restrict__ w2d, const float* __restrict__ b2d, const float* __restrict__ tpw,
    const float* __restrict__ yraw, const float* __restrict__ qp_arr,
    const float* __restrict__ kpack, const float* __restrict__ vpack,
    const float* __restrict__ sq_arr, const float* __restrict__ rotm,
    const float* __restrict__ trans,
    float* __restrict__ fin)
{
    __shared__ float x_l[2][MT2_][132];   // 16.9 KB
    __shared__ float w2_l[12][128];       // 6.1 KB
    __shared__ float tl[2][12][20];       // p values
    __shared__ float at2_l[2][MT2_][13];
    __shared__ float qs_l[2][192];
    __shared__ float qp_l[2][144];
    __shared__ float sq_l[2][12];
    __shared__ float rt_l[2][12];
    __shared__ float pw_l[12], b2_l[12];
    __shared__ float maskn_l[2];
    __shared__ float rmax_l[2][12], rsum_l[2][12], alph_l[2][12];
    __shared__ float pg_l[2][288];

    const int t = threadIdx.x;
    const int n0 = blockIdx.x * 2;

    // thread mappings
    const int sn = t >> 7;            // staging + res2d: n (0..1)
    const int sm = (t >> 3) & 15;     // staging: m
    const int k8 = t & 7;             // staging: c-octant (16 c)
    const int hx = t >> 4;            // P2: h (active < 12)
    const int m2 = t & 15;            // P2: m
    const int cc = t & 127;           // res2d: c
    const int jF = 2 * t;             // resF: j pair (t < 240)
    const int hF = (jF < 192) ? (jF >> 4) : (((jF - 192) % 96) >> 3);

    float accR[12];
    #pragma unroll
    for (int e = 0; e < 12; ++e) accR[e] = 0.f;
    float accF[4] = {0.f, 0.f, 0.f, 0.f};
    float4 xpf[4];

    // ---- prologue ----
    for (int i = t; i < 1536; i += 256) { int c = i / 12, h = i % 12; w2_l[h][c] = w2d[i]; }
    if (t < 192) { qs_l[0][t] = yraw[(size_t)n0 * 1152 + t]; qs_l[1][t] = yraw[(size_t)(n0 + 1) * 1152 + t]; }
    if (t < 144) { qp_l[0][t] = qp_arr[(size_t)n0 * 144 + t]; qp_l[1][t] = qp_arr[(size_t)(n0 + 1) * 144 + t]; }
    if (t < 24)  { sq_l[t / 12][t % 12] = sq_arr[(size_t)(n0 + t / 12) * 12 + (t % 12)]; }
    if (t >= 32 && t < 56) {
        int i = t - 32, nl = i / 12, r = i % 12;
        rt_l[nl][r] = (r < 9) ? rotm[(n0 + nl) * 9 + r] : trans[(n0 + nl) * 3 + (r - 9)];
    }
    if (t >= 64 && t < 76)  pw_l[t - 64] = 0.13608276348795434f * log1pf(__expf(tpw[t - 64]));
    if (t >= 96 && t < 108) b2_l[t - 96] = b2d[t - 96];
    if (t >= 128 && t < 130) maskn_l[t - 128] = mask[n0 + (t - 128)];
    if (t >= 160 && t < 184) { int i = t - 160; rmax_l[i / 12][i % 12] = -3.0e38f; }
    if (t >= 192 && t < 216) { int i = t - 192; rsum_l[i / 12][i % 12] = 0.f; }

    // initial x prefetch (tile 0)
    #pragma unroll
    for (int f = 0; f < 4; ++f)
        xpf[f] = *(const float4*)&x2d[((size_t)(n0 + sn) * NN_ + sm) * 128 + k8 * 16 + f * 4];
    __syncthreads();

    for (int mt = 0; mt < NT2_; ++mt) {
        const int m0 = mt * MT2_;
        // ===== P1: commit x prefetch to LDS + att2d partial dots =====
        #pragma unroll
        for (int f = 0; f < 4; ++f)
            *(float4*)&x_l[sn][sm][k8 * 16 + f * 4] = xpf[f];
        {
            float at2[12];
            #pragma unroll
            for (int h = 0; h < 12; ++h) {
                float s = 0.f;
                #pragma unroll
                for (int f = 0; f < 4; ++f) {
                    float4 wv = *(const float4*)&w2_l[h][k8 * 16 + f * 4];
                    s += xpf[f].x * wv.x + xpf[f].y * wv.y + xpf[f].z * wv.z + xpf[f].w * wv.w;
                }
                at2[h] = s;
            }
            #pragma unroll
            for (int d = 1; d <= 4; d <<= 1) {
                #pragma unroll
                for (int h = 0; h < 12; ++h) at2[h] += __shfl_xor(at2[h], d);
            }
            if (k8 == 0) {
                #pragma unroll
                for (int h = 0; h < 12; ++h) at2_l[sn][sm][h] = at2[h];
            }
        }
        __syncthreads();

        // ===== P2: logits + online softmax; all threads prefetch next x =====
        {
            int m1 = (mt + 1 == NT2_) ? 0 : (m0 + MT2_);
            #pragma unroll
            for (int f = 0; f < 4; ++f)
                xpf[f] = *(const float4*)&x2d[((size_t)(n0 + sn) * NN_ + m1 + sm) * 128 + k8 * 16 + f * 4];
        }
        if (hx < 12) {
            const int h = hx;
            const float* kr = kpack + (size_t)(m0 + m2) * 352;
            float4 ksA = *(const float4*)&kr[h * 16 + 0];
            float4 ksB = *(const float4*)&kr[h * 16 + 4];
            float4 ksC = *(const float4*)&kr[h * 16 + 8];
            float4 ksD = *(const float4*)&kr[h * 16 + 12];
            float4 kpA = *(const float4*)&kr[192 + h * 4];
            float4 kpB = *(const float4*)&kr[192 + 48 + h * 4];
            float4 kpC = *(const float4*)&kr[192 + 96 + h * 4];
            float skm = kr[336 + h];
            float mkm = mask[m0 + m2];
            float pwh = pw_l[h];
            #pragma unroll
            for (int nn = 0; nn < 2; ++nn) {
                const float4* qsn = (const float4*)&qs_l[nn][h * 16];
                float dqs = qsn[0].x*ksA.x + qsn[0].y*ksA.y + qsn[0].z*ksA.z + qsn[0].w*ksA.w
                          + qsn[1].x*ksB.x + qsn[1].y*ksB.y + qsn[1].z*ksB.z + qsn[1].w*ksB.w
                          + qsn[2].x*ksC.x + qsn[2].y*ksC.y + qsn[2].z*ksC.z + qsn[2].w*ksC.w
                          + qsn[3].x*ksD.x + qsn[3].y*ksD.y + qsn[3].z*ksD.z + qsn[3].w*ksD.w;
                float4 qA = *(const float4*)&qp_l[nn][h * 4];
                float4 qB = *(const float4*)&qp_l[nn][48 + h * 4];
                float4 qC = *(const float4*)&qp_l[nn][96 + h * 4];
                float qk = qA.x*kpA.x + qA.y*kpA.y + qA.z*kpA.z + qA.w*kpA.w
                         + qB.x*kpB.x + qB.y*kpB.y + qB.z*kpB.z + qB.w*kpB.w
                         + qC.x*kpC.x + qC.y*kpC.y + qC.z*kpC.z + qC.w*kpC.w;
                float lg = 0.14433756729740643f * dqs
                         + pwh * qk - 0.5f * pwh * (sq_l[nn][h] + skm)
                         + 0.57735026918962576f * (at2_l[nn][m2][h] + b2_l[h])
                         - 100000.0f * (1.0f - maskn_l[nn] * mkm);
                float tm = lg;
                tm = fmaxf(tm, __shfl_xor(tm, 1));
                tm = fmaxf(tm, __shfl_xor(tm, 2));
                tm = fmaxf(tm, __shfl_xor(tm, 4));
                tm = fmaxf(tm, __shfl_xor(tm, 8));
                float om = rmax_l[nn][h];
                float nm = fmaxf(om, tm);
                float p = __expf(lg - nm);
                tl[nn][h][m2] = p;
                float ps = p;
                ps += __shfl_xor(ps, 1);
                ps += __shfl_xor(ps, 2);
                ps += __shfl_xor(ps, 4);
                ps += __shfl_xor(ps, 8);
                if (m2 == 0) {
                    float al = __expf(om - nm);
                    rmax_l[nn][h] = nm;
                    alph_l[nn][h] = al;
                    rsum_l[nn][h] = rsum_l[nn][h] * al + ps;
                }
            }
        }
        __syncthreads();

        // ===== P5: rescale + res2d (x from LDS, p broadcast) =====
        {
            #pragma unroll
            for (int h = 0; h < 12; ++h) accR[h] *= alph_l[sn][h];
            #pragma unroll
            for (int mm = 0; mm < MT2_; mm += 4) {
                float x0  = x_l[sn][mm + 0][cc];
                float x1  = x_l[sn][mm + 1][cc];
                float x2v = x_l[sn][mm + 2][cc];
                float x3  = x_l[sn][mm + 3][cc];
                #pragma unroll
                for (int h = 0; h < 12; ++h) {
                    float4 pv = *(const float4*)&tl[sn][h][mm];
                    accR[h] += pv.x * x0 + pv.y * x1 + pv.z * x2v + pv.w * x3;
                }
            }
        }
        // ===== P6: resF (v from L2, shared by both n) =====
        if (t < 240) {
            float a0 = alph_l[0][hF], a1 = alph_l[1][hF];
            accF[0] *= a0; accF[1] *= a0; accF[2] *= a1; accF[3] *= a1;
            const float* vb = vpack + (size_t)m0 * 480 + jF;
            #pragma unroll
            for (int mm = 0; mm < MT2_; mm += 4) {
                float4 p0 = *(const float4*)&tl[0][hF][mm];
                float4 p1 = *(const float4*)&tl[1][hF][mm];
                float2 v0 = *(const float2*)&vb[(size_t)(mm + 0) * 480];
                float2 v1 = *(const float2*)&vb[(size_t)(mm + 1) * 480];
                float2 v2 = *(const float2*)&vb[(size_t)(mm + 2) * 480];
                float2 v3 = *(const float2*)&vb[(size_t)(mm + 3) * 480];
                accF[0] += p0.x * v0.x + p0.y * v1.x + p0.z * v2.x + p0.w * v3.x;
                accF[1] += p0.x * v0.y + p0.y * v1.y + p0.z * v2.y + p0.w * v3.y;
                accF[2] += p1.x * v0.x + p1.y * v1.x + p1.z * v2.x + p1.w * v3.x;
                accF[3] += p1.x * v0.y + p1.y * v1.y + p1.z * v2.y + p1.w * v3.y;
            }
        }
        __syncthreads();
    }

    // ================= epilogue =================
    {
        #pragma unroll
        for (int h = 0; h < 12; ++h) {
            float v = accR[h] / rsum_l[sn][h];
            fin[(size_t)(n0 + sn) * DOUT_ + 576 + (size_t)h * 128 + cc] = v;
        }
    }
    if (t < 240) {
        float i0 = 1.f / rsum_l[0][hF], i1 = 1.f / rsum_l[1][hF];
        float vA0 = accF[0] * i0, vA1 = accF[1] * i0;
        float vB0 = accF[2] * i1, vB1 = accF[3] * i1;
        if (jF < 192) {
            fin[(size_t)n0 * DOUT_ + jF] = vA0;       fin[(size_t)n0 * DOUT_ + jF + 1] = vA1;
            fin[(size_t)(n0 + 1) * DOUT_ + jF] = vB0; fin[(size_t)(n0 + 1) * DOUT_ + jF + 1] = vB1;
        } else {
            pg_l[0][jF - 192] = vA0; pg_l[0][jF - 191] = vA1;
            pg_l[1][jF - 192] = vB0; pg_l[1][jF - 191] = vB1;
        }
    }
    __syncthreads();
    if (t < 192) {
        const int n = t / 96, k = t % 96;
        const float* R = rt_l[n];
        float c0 = pg_l[n][k]       - R[9];
        float c1 = pg_l[n][96 + k]  - R[10];
        float c2 = pg_l[n][192 + k] - R[11];
        float r0 = R[0] * c0 + R[3] * c1 + R[6] * c2;
        float r1 = R[1] * c0 + R[4] * c1 + R[7] * c2;
        float r2 = R[2] * c0 + R[5] * c1 + R[8] * c2;
        size_t base = (size_t)(n0 + n) * DOUT_;
        fin[base + 192 + k] = r0;
        fin[base + 288 + k] = r1;
        fin[base + 384 + k] = r2;
        fin[base + 480 + k] = sqrtf(1e-8f + r0 * r0 + r1 * r1 + r2 * r2);
    }
}

// ---------------- K5: out partials, split-K over 4 chunks of 528 ----------------
__global__ __launch_bounds__(256) void k_out(
    const float* __restrict__ fin, const float* __restrict__ wo,
    float* __restrict__ pout)
{
    __shared__ float a_l[64 * 52];
    __shared__ float b_l[48 * 68];
    const int t = threadIdx.x;
    const int m0 = blockIdx.x * 64, n0 = blockIdx.y * 64, kc = blockIdx.z;
    const int tx = t & 15, ty = t >> 4;
    float acc[4][4] = {};
    for (int k0 = kc * 528; k0 < kc * 528 + 528; k0 += 48) {
        #pragma unroll
        for (int e = 0; e < 3; ++e) {
            int idx = t + 256 * e;
            int r = idx / 12, c4 = (idx % 12) * 4;
            *(float4*)&a_l[r * 52 + c4] = *(const float4*)&fin[(size_t)(m0 + r) * DOUT_ + k0 + c4];
        }
        #pragma unroll
        for (int e = 0; e < 3; ++e) {
            int idx = t + 256 * e;
            int r = idx >> 4, c4 = (idx & 15) * 4;
            *(float4*)&b_l[r * 68 + c4] = *(const float4*)&wo[(size_t)(k0 + r) * 384 + n0 + c4];
        }
        __syncthreads();
        #pragma unroll 4
        for (int k = 0; k < 48; ++k) {
            float4 bv = *(const float4*)&b_l[k * 68 + tx * 4];
            #pragma unroll
            for (int i = 0; i < 4; ++i) {
                float av = a_l[(ty * 4 + i) * 52 + k];
                acc[i][0] += av * bv.x; acc[i][1] += av * bv.y;
                acc[i][2] += av * bv.z; acc[i][3] += av * bv.w;
            }
        }
        __syncthreads();
    }
    float* pr = pout + (size_t)kc * 393216;
    #pragma unroll
    for (int i = 0; i < 4; ++i) {
        float4 o;
        o.x = acc[i][0]; o.y = acc[i][1]; o.z = acc[i][2]; o.w = acc[i][3];
        *(float4*)&pr[(size_t)(m0 + ty * 4 + i) * 384 + n0 + tx * 4] = o;
    }
}

// ---------------- K6: sum split-K partials + bias ----------------
__global__ __launch_bounds__(256) void k_fin(
    const float* __restrict__ pout, const float* __restrict__ bo, float* __restrict__ out)
{
    int idx = blockIdx.x * 256 + threadIdx.x;
    float4 a = *(const float4*)&pout[(size_t)idx * 4];
    float4 b = *(const float4*)&pout[393216 + (size_t)idx * 4];
    float4 c = *(const float4*)&pout[786432 + (size_t)idx * 4];
    float4 d = *(const float4*)&pout[1179648 + (size_t)idx * 4];
    float4 bias = *(const float4*)&bo[(idx % 96) * 4];
    float4 o;
    o.x = a.x + b.x + c.x + d.x + bias.x;
    o.y = a.y + b.y + c.y + d.y + bias.y;
    o.z = a.z + b.z + c.z + d.z + bias.z;
    o.w = a.w + b.w + c.w + d.w + bias.w;
    *(float4*)&out[(size_t)idx * 4] = o;
}

extern "C" void kernel_launch(void* const* d_in, const int* in_sizes, int n_in,
                              void* d_out, int out_size, void* d_ws, size_t ws_size,
                              hipStream_t stream) {
    const float* in1   = (const float*)d_in[0];
    const float* x2d   = (const float*)d_in[1];
    const float* mask  = (const float*)d_in[2];
    const float* rotm  = (const float*)d_in[3];
    const float* trans = (const float*)d_in[4];
    const float* wq    = (const float*)d_in[5];
    const float* bq    = (const float*)d_in[6];
    const float* wkv   = (const float*)d_in[7];
    const float* bkv   = (const float*)d_in[8];
    const float* wqp   = (const float*)d_in[9];
    const float* bqp   = (const float*)d_in[10];
    const float* wkvp  = (const float*)d_in[11];
    const float* bkvp  = (const float*)d_in[12];
    const float* w2d   = (const float*)d_in[13];
    const float* b2d   = (const float*)d_in[14];
    const float* tpw   = (const float*)d_in[15];
    const float* wo    = (const float*)d_in[16];
    const float* bo    = (const float*)d_in[17];
    float* out = (float*)d_out;

    float* ws = (float*)d_ws;
    float* yraw   = ws;                    // 1,179,648
    float* qp_arr = yraw + 1179648;        //   147,456
    float* kpack  = qp_arr + 147456;       //   360,448
    float* vpack  = kpack + 360448;        //   491,520
    float* sq_arr = vpack + 491520;        //    12,288
    float* fin    = sq_arr + 12288;        // 2,162,688
    float* pout   = fin + 2162688;         // 1,572,864

    hipLaunchKernelGGL(k_gemm1, dim3(16, 18), dim3(256), 0, stream,
        in1, wq, bq, wkv, bkv, wqp, bqp, wkvp, bkvp, yraw);
    hipLaunchKernelGGL(k_rot, dim3(256), dim3(256), 0, stream,
        yraw, rotm, trans, qp_arr, kpack, vpack, sq_arr);
    hipLaunchKernelGGL(k_attn4, dim3(512), dim3(256), 0, stream,
        x2d, mask, w2d, b2d, tpw, yraw, qp_arr, kpack, vpack, sq_arr, rotm, trans, fin);
    hipLaunchKernelGGL(k_out, dim3(16, 6, 4), dim3(256), 0, stream, fin, wo, pout);
    hipLaunchKernelGGL(k_fin, dim3(384), dim3(256), 0, stream, pout, bo, out);
}

// Round 7
// 658.355 us; speedup vs baseline: 4.3195x; 1.4210x over previous
//
#include <hip/hip_runtime.h>
#include <math.h>

#define NN_ 1024
#define DOUT_ 2112
#define NOUT_ 384

// ---------------- K1: yraw[1024][1152] = in1 @ [wq|wkv|wqp|wkvp] + bias ----------------
__global__ __launch_bounds__(256) void k_gemm1(
    const float* __restrict__ in1,
    const float* __restrict__ wq, const float* __restrict__ bq,
    const float* __restrict__ wkv, const float* __restrict__ bkv,
    const float* __restrict__ wqp, const float* __restrict__ bqp,
    const float* __restrict__ wkvp, const float* __restrict__ bkvp,
    float* __restrict__ yraw)
{
    __shared__ float a_l[64 * 36];
    __shared__ float b_l[32 * 68];
    const int t = threadIdx.x;
    const int m0 = blockIdx.x * 64, j0 = blockIdx.y * 64;
    const int tx = t & 15, ty = t >> 4;
    float acc[4][4] = {};
    for (int k0 = 0; k0 < 384; k0 += 32) {
        #pragma unroll
        for (int e = 0; e < 2; ++e) {
            int idx = t + 256 * e;
            int r = idx >> 3, c4 = (idx & 7) * 4;
            *(float4*)&a_l[r * 36 + c4] = *(const float4*)&in1[(size_t)(m0 + r) * 384 + k0 + c4];
        }
        #pragma unroll
        for (int e = 0; e < 2; ++e) {
            int idx = t + 256 * e;
            int r = idx >> 4, c4 = (idx & 15) * 4;
            int j = j0 + c4;
            const float* w; int ncol, jj;
            if (j < 192)      { w = wq;   ncol = 192; jj = j; }
            else if (j < 576) { w = wkv;  ncol = 384; jj = j - 192; }
            else if (j < 720) { w = wqp;  ncol = 144; jj = j - 576; }
            else              { w = wkvp; ncol = 432; jj = j - 720; }
            *(float4*)&b_l[r * 68 + c4] = *(const float4*)&w[(size_t)(k0 + r) * ncol + jj];
        }
        __syncthreads();
        #pragma unroll 8
        for (int k = 0; k < 32; ++k) {
            float4 bv = *(const float4*)&b_l[k * 68 + tx * 4];
            #pragma unroll
            for (int i = 0; i < 4; ++i) {
                float av = a_l[(ty * 4 + i) * 36 + k];
                acc[i][0] += av * bv.x; acc[i][1] += av * bv.y;
                acc[i][2] += av * bv.z; acc[i][3] += av * bv.w;
            }
        }
        __syncthreads();
    }
    int j = j0 + tx * 4;
    float4 bias;
    {
        const float* b; int jj;
        if (j < 192)      { b = bq;   jj = j; }
        else if (j < 576) { b = bkv;  jj = j - 192; }
        else if (j < 720) { b = bqp;  jj = j - 576; }
        else              { b = bkvp; jj = j - 720; }
        bias = *(const float4*)&b[jj];
    }
    #pragma unroll
    for (int i = 0; i < 4; ++i) {
        float4 o;
        o.x = acc[i][0] + bias.x; o.y = acc[i][1] + bias.y;
        o.z = acc[i][2] + bias.z; o.w = acc[i][3] + bias.w;
        *(float4*)&yraw[(size_t)(m0 + ty * 4 + i) * 1152 + j] = o;
    }
}

// ---------------- K2: rotations + packing ----------------
// kpack[n][352]: [0:192 ks(h*16+s)] [192:336 kp(a*48+h*4+p)] [336:348 sk(h)]
// vpack[n][480]: [0:192 vs(h*16+s)] [192:480 vp(a*96+h*8+p)]
__global__ __launch_bounds__(256) void k_rot(
    const float* __restrict__ yraw, const float* __restrict__ rotm, const float* __restrict__ trans,
    float* __restrict__ qp_arr, float* __restrict__ kpack, float* __restrict__ vpack,
    float* __restrict__ sq_arr)
{
    __shared__ float rt_l[4][12];
    const int t = threadIdx.x;
    const int n0 = blockIdx.x * 4;
    if (t < 48) {
        int n_ = t / 12, i = t % 12;
        rt_l[n_][i] = (i < 9) ? rotm[(n0 + n_) * 9 + i] : trans[(n0 + n_) * 3 + (i - 9)];
    }
    __syncthreads();
    const int n_ = t >> 6, l = t & 63;
    const int n = n0 + n_;
    const float* y = yraw + (size_t)n * 1152;
    const float* R = rt_l[n_];
    #pragma unroll
    for (int jj = 0; jj < 9; ++jj) {
        int o = l + 64 * jj;
        if (o < 144) {
            int a = o / 48, kk = o % 48;
            float v = R[9 + a] + R[a*3+0] * y[576 + kk] + R[a*3+1] * y[576 + 48 + kk] + R[a*3+2] * y[576 + 96 + kk];
            qp_arr[(size_t)n * 144 + o] = v;
        } else if (o < 288) {
            int o2 = o - 144;
            int a = o2 / 48, r2 = o2 % 48;
            int kk = (r2 >> 2) * 12 + (r2 & 3);
            float v = R[9 + a] + R[a*3+0] * y[720 + kk] + R[a*3+1] * y[720 + 144 + kk] + R[a*3+2] * y[720 + 288 + kk];
            kpack[(size_t)n * 352 + 192 + o2] = v;
        } else {
            int o3 = o - 288;
            int a = o3 / 96, r2 = o3 % 96;
            int kk = (r2 >> 3) * 12 + 4 + (r2 & 7);
            float v = R[9 + a] + R[a*3+0] * y[720 + kk] + R[a*3+1] * y[720 + 144 + kk] + R[a*3+2] * y[720 + 288 + kk];
            vpack[(size_t)n * 480 + 192 + o3] = v;
        }
    }
    #pragma unroll
    for (int jj = 0; jj < 3; ++jj) {
        int o = l + 64 * jj;  // 0..191
        int h = o >> 4, r2 = o & 15;
        kpack[(size_t)n * 352 + o] = y[192 + h * 32 + r2];
        vpack[(size_t)n * 480 + o] = y[192 + h * 32 + 16 + r2];
    }
    if (l < 24) {
        int which = l / 12, h = l % 12;
        int base = (which == 0) ? 576 : 720;
        int stride = (which == 0) ? 48 : 144;
        float s = 0.f;
        #pragma unroll
        for (int a = 0; a < 3; ++a) {
            #pragma unroll
            for (int p = 0; p < 4; ++p) {
                int kk = (which == 0) ? (h * 4 + p) : (h * 12 + p);
                float v = R[9 + a] + R[a*3+0] * y[base + kk] + R[a*3+1] * y[base + stride + kk] + R[a*3+2] * y[base + 2 * stride + kk];
                s += v * v;
            }
        }
        if (which == 0) sq_arr[(size_t)n * 12 + h] = s;
        else            kpack[(size_t)n * 352 + 336 + h] = s;
    }
}

// ---------------- K3: fused flash IPA, one n per block, MT=64, 256 threads ----------------
// plain __launch_bounds__(256): any min-waves hint makes the allocator cap at 64 VGPR
// and spill gigabytes to scratch (rounds 3-5 evidence).
__global__ __launch_bounds__(256) void k_attn5(
    const float* __restrict__ x2d, const float* __restrict__ mask,
    const float* __restrict__ w2d, const float* __restrict__ b2d, const float* __restrict__ tpw,
    const float* __restrict__ yraw, const float* __restrict__ qp_arr,
    const float* __restrict__ kpack, const float* __restrict__ vpack,
    const float* __restrict__ sq_arr, const float* __restrict__ rotm,
    const float* __restrict__ trans,
    float* __restrict__ fin)
{
    __shared__ float x_l[64][132];      // 33.8 KB, pad 132: stage f4 writes hit all 32 banks
    __shared__ float w2r_l[4 * 388];    // 6.2 KB, per-q4 blocks stride 388 -> distinct bank-quads
    __shared__ float tl[12][68];        // 3.3 KB, pad 68: 16B-aligned rows
    __shared__ float at2_l[64][13];     // 3.3 KB
    __shared__ float qs_l[192], qp_l[144];
    __shared__ float sq_l[12], pw_l[12], b2_l[12];
    __shared__ float rmax_l[12], rsum_l[12], alph_l[12];
    __shared__ float rt_l[12];
    __shared__ float pg_l[288];

    const int t = threadIdx.x;
    const int n = blockIdx.x;

    // thread maps
    const int sm = t >> 2, q4 = t & 3;     // stage: m (64), c-quarter (32 c)
    const int m3 = t & 63, hg = t >> 6;    // logits: lane=m, wave=h-trio
    const int cR = t & 63, hgR = t >> 6;   // res2d: c, h-trio
    const int jF = 2 * t;                  // resF: j pair (t<240)
    const int hF = (jF < 192) ? (jF >> 4) : (((jF - 192) % 96) >> 3);

    float acc[3][2] = {};
    float accF0 = 0.f, accF1 = 0.f;
    float4 xpf[8];

    // ---- prologue ----
    for (int i = t; i < 1536; i += 256) {
        int q = i / 384, r = i % 384;
        int f = r / 48, r2 = r % 48;
        int h = r2 >> 2, ii = r2 & 3;
        int c = q * 32 + f * 4 + ii;
        w2r_l[q * 388 + f * 48 + h * 4 + ii] = w2d[c * 12 + h];
    }
    if (t < 192) qs_l[t] = yraw[(size_t)n * 1152 + t];
    if (t < 144) qp_l[t] = qp_arr[(size_t)n * 144 + t];
    if (t < 12) {
        sq_l[t] = sq_arr[(size_t)n * 12 + t];
        pw_l[t] = 0.13608276348795434f * log1pf(__expf(tpw[t]));
        b2_l[t] = b2d[t];
        rmax_l[t] = -3.0e38f; rsum_l[t] = 0.f;
        rt_l[t] = (t < 9) ? rotm[n * 9 + t] : trans[n * 3 + (t - 9)];
    }
    const float maskn = mask[n];

    // initial x prefetch (tile 0)
    {
        const float* xr = x2d + ((size_t)n * NN_ + sm) * 128 + q4 * 32;
        #pragma unroll
        for (int f = 0; f < 8; ++f) xpf[f] = *(const float4*)&xr[4 * f];
    }
    __syncthreads();

    for (int mt = 0; mt < 16; ++mt) {
        const int m0 = mt * 64;
        // ===== STAGE: commit xpf -> x_l, compute at2 partials from registers =====
        #pragma unroll
        for (int f = 0; f < 8; ++f)
            *(float4*)&x_l[sm][q4 * 32 + 4 * f] = xpf[f];
        {
            float at2[12];
            #pragma unroll
            for (int h = 0; h < 12; ++h) at2[h] = 0.f;
            #pragma unroll
            for (int f = 0; f < 8; ++f) {
                #pragma unroll
                for (int h = 0; h < 12; ++h) {
                    float4 wv = *(const float4*)&w2r_l[q4 * 388 + f * 48 + h * 4];
                    at2[h] += xpf[f].x * wv.x + xpf[f].y * wv.y + xpf[f].z * wv.z + xpf[f].w * wv.w;
                }
            }
            #pragma unroll
            for (int h = 0; h < 12; ++h) {
                at2[h] += __shfl_xor(at2[h], 1);
                at2[h] += __shfl_xor(at2[h], 2);
            }
            if (q4 == 0) {
                #pragma unroll
                for (int h = 0; h < 12; ++h) at2_l[sm][h] = at2[h];
            }
        }
        __syncthreads();   // (1) x_l/at2_l ready

        // ===== LOGITS + wave-internal online softmax =====
        {
            // prefetch next x tile (overlaps with L2 kpack reads + compute)
            int m1 = (mt + 1 == 16) ? 0 : (m0 + 64);
            const float* xr = x2d + ((size_t)n * NN_ + m1 + sm) * 128 + q4 * 32;
            #pragma unroll
            for (int f = 0; f < 8; ++f) xpf[f] = *(const float4*)&xr[4 * f];
        }
        {
            const float* kr = kpack + (size_t)(m0 + m3) * 352;
            const float mkm = mask[m0 + m3];
            const float mko = 100000.0f * (1.0f - maskn * mkm);
            #pragma unroll
            for (int e = 0; e < 3; ++e) {
                const int h = hg * 3 + e;
                float dqs;
                {
                    const float4* qsn = (const float4*)&qs_l[h * 16];
                    float4 kA = *(const float4*)&kr[h * 16 + 0];
                    float4 kB = *(const float4*)&kr[h * 16 + 4];
                    float4 kC = *(const float4*)&kr[h * 16 + 8];
                    float4 kD = *(const float4*)&kr[h * 16 + 12];
                    dqs = qsn[0].x*kA.x + qsn[0].y*kA.y + qsn[0].z*kA.z + qsn[0].w*kA.w
                        + qsn[1].x*kB.x + qsn[1].y*kB.y + qsn[1].z*kB.z + qsn[1].w*kB.w
                        + qsn[2].x*kC.x + qsn[2].y*kC.y + qsn[2].z*kC.z + qsn[2].w*kC.w
                        + qsn[3].x*kD.x + qsn[3].y*kD.y + qsn[3].z*kD.z + qsn[3].w*kD.w;
                }
                float qk;
                {
                    float4 pA = *(const float4*)&kr[192 + h * 4];
                    float4 pB = *(const float4*)&kr[192 + 48 + h * 4];
                    float4 pC = *(const float4*)&kr[192 + 96 + h * 4];
                    float4 qA = *(const float4*)&qp_l[h * 4];
                    float4 qB = *(const float4*)&qp_l[48 + h * 4];
                    float4 qC = *(const float4*)&qp_l[96 + h * 4];
                    qk = qA.x*pA.x + qA.y*pA.y + qA.z*pA.z + qA.w*pA.w
                       + qB.x*pB.x + qB.y*pB.y + qB.z*pB.z + qB.w*pB.w
                       + qC.x*pC.x + qC.y*pC.y + qC.z*pC.z + qC.w*pC.w;
                }
                float pwh = pw_l[h];
                float lg = 0.14433756729740643f * dqs
                         + pwh * qk - 0.5f * pwh * (sq_l[h] + kr[336 + h])
                         + 0.57735026918962576f * (at2_l[m3][h] + b2_l[h])
                         - mko;
                // wave-internal softmax over 64 m
                float tm = lg;
                tm = fmaxf(tm, __shfl_xor(tm, 1));
                tm = fmaxf(tm, __shfl_xor(tm, 2));
                tm = fmaxf(tm, __shfl_xor(tm, 4));
                tm = fmaxf(tm, __shfl_xor(tm, 8));
                tm = fmaxf(tm, __shfl_xor(tm, 16));
                tm = fmaxf(tm, __shfl_xor(tm, 32));
                float om = rmax_l[h];
                float nm = fmaxf(om, tm);
                float p = __expf(lg - nm);
                tl[h][m3] = p;
                float ps = p;
                ps += __shfl_xor(ps, 1);
                ps += __shfl_xor(ps, 2);
                ps += __shfl_xor(ps, 4);
                ps += __shfl_xor(ps, 8);
                ps += __shfl_xor(ps, 16);
                ps += __shfl_xor(ps, 32);
                if (m3 == 0) {
                    float al = __expf(om - nm);
                    rmax_l[h] = nm;
                    alph_l[h] = al;
                    rsum_l[h] = rsum_l[h] * al + ps;
                }
            }
        }
        __syncthreads();   // (2) p/alph ready

        // ===== ACCUM: res2d (LDS) + resF (L2) =====
        {
            const int hb = hgR * 3;
            float al0 = alph_l[hb], al1 = alph_l[hb + 1], al2 = alph_l[hb + 2];
            acc[0][0] *= al0; acc[0][1] *= al0;
            acc[1][0] *= al1; acc[1][1] *= al1;
            acc[2][0] *= al2; acc[2][1] *= al2;
            #pragma unroll 4
            for (int mm = 0; mm < 64; mm += 4) {
                float4 p0 = *(const float4*)&tl[hb + 0][mm];
                float4 p1 = *(const float4*)&tl[hb + 1][mm];
                float4 p2 = *(const float4*)&tl[hb + 2][mm];
                float pa0[4] = {p0.x, p0.y, p0.z, p0.w};
                float pa1[4] = {p1.x, p1.y, p1.z, p1.w};
                float pa2[4] = {p2.x, p2.y, p2.z, p2.w};
                #pragma unroll
                for (int q = 0; q < 4; ++q) {
                    float xa = x_l[mm + q][cR];
                    float xb = x_l[mm + q][cR + 64];
                    acc[0][0] += pa0[q] * xa; acc[0][1] += pa0[q] * xb;
                    acc[1][0] += pa1[q] * xa; acc[1][1] += pa1[q] * xb;
                    acc[2][0] += pa2[q] * xa; acc[2][1] += pa2[q] * xb;
                }
            }
        }
        if (t < 240) {
            float alf = alph_l[hF];
            accF0 *= alf; accF1 *= alf;
            const float* vb = vpack + (size_t)m0 * 480 + jF;
            #pragma unroll 4
            for (int mm = 0; mm < 64; mm += 4) {
                float4 p = *(const float4*)&tl[hF][mm];
                float2 v0 = *(const float2*)&vb[(size_t)(mm + 0) * 480];
                float2 v1 = *(const float2*)&vb[(size_t)(mm + 1) * 480];
                float2 v2 = *(const float2*)&vb[(size_t)(mm + 2) * 480];
                float2 v3 = *(const float2*)&vb[(size_t)(mm + 3) * 480];
                accF0 += p.x * v0.x + p.y * v1.x + p.z * v2.x + p.w * v3.x;
                accF1 += p.x * v0.y + p.y * v1.y + p.z * v2.y + p.w * v3.y;
            }
        }
        __syncthreads();   // (3) protect x_l/tl/at2_l for next stage
    }

    // ================= epilogue =================
    {
        const int hb = hgR * 3;
        #pragma unroll
        for (int e = 0; e < 3; ++e) {
            float inv = 1.f / rsum_l[hb + e];
            fin[(size_t)n * DOUT_ + 576 + (size_t)(hb + e) * 128 + cR]      = acc[e][0] * inv;
            fin[(size_t)n * DOUT_ + 576 + (size_t)(hb + e) * 128 + cR + 64] = acc[e][1] * inv;
        }
    }
    if (t < 240) {
        float inv = 1.f / rsum_l[hF];
        float vA = accF0 * inv, vB = accF1 * inv;
        if (jF < 192) {
            fin[(size_t)n * DOUT_ + jF]     = vA;
            fin[(size_t)n * DOUT_ + jF + 1] = vB;
        } else {
            pg_l[jF - 192] = vA;
            pg_l[jF - 191] = vB;
        }
    }
    __syncthreads();
    if (t < 96) {
        const int k = t;
        float c0 = pg_l[k]       - rt_l[9];
        float c1 = pg_l[96 + k]  - rt_l[10];
        float c2 = pg_l[192 + k] - rt_l[11];
        float r0 = rt_l[0] * c0 + rt_l[3] * c1 + rt_l[6] * c2;
        float r1 = rt_l[1] * c0 + rt_l[4] * c1 + rt_l[7] * c2;
        float r2 = rt_l[2] * c0 + rt_l[5] * c1 + rt_l[8] * c2;
        size_t base = (size_t)n * DOUT_;
        fin[base + 192 + k] = r0;
        fin[base + 288 + k] = r1;
        fin[base + 384 + k] = r2;
        fin[base + 480 + k] = sqrtf(1e-8f + r0 * r0 + r1 * r1 + r2 * r2);
    }
}

// ---------------- K5: out partials, split-K over 4 chunks of 528 ----------------
__global__ __launch_bounds__(256) void k_out(
    const float* __restrict__ fin, const float* __restrict__ wo,
    float* __restrict__ pout)
{
    __shared__ float a_l[64 * 52];
    __shared__ float b_l[48 * 68];
    const int t = threadIdx.x;
    const int m0 = blockIdx.x * 64, n0 = blockIdx.y * 64, kc = blockIdx.z;
    const int tx = t & 15, ty = t >> 4;
    float acc[4][4] = {};
    for (int k0 = kc * 528; k0 < kc * 528 + 528; k0 += 48) {
        #pragma unroll
        for (int e = 0; e < 3; ++e) {
            int idx = t + 256 * e;
            int r = idx / 12, c4 = (idx % 12) * 4;
            *(float4*)&a_l[r * 52 + c4] = *(const float4*)&fin[(size_t)(m0 + r) * DOUT_ + k0 + c4];
        }
        #pragma unroll
        for (int e = 0; e < 3; ++e) {
            int idx = t + 256 * e;
            int r = idx >> 4, c4 = (idx & 15) * 4;
            *(float4*)&b_l[r * 68 + c4] = *(const float4*)&wo[(size_t)(k0 + r) * 384 + n0 + c4];
        }
        __syncthreads();
        #pragma unroll 4
        for (int k = 0; k < 48; ++k) {
            float4 bv = *(const float4*)&b_l[k * 68 + tx * 4];
            #pragma unroll
            for (int i = 0; i < 4; ++i) {
                float av = a_l[(ty * 4 + i) * 52 + k];
                acc[i][0] += av * bv.x; acc[i][1] += av * bv.y;
                acc[i][2] += av * bv.z; acc[i][3] += av * bv.w;
            }
        }
        __syncthreads();
    }
    float* pr = pout + (size_t)kc * 393216;
    #pragma unroll
    for (int i = 0; i < 4; ++i) {
        float4 o;
        o.x = acc[i][0]; o.y = acc[i][1]; o.z = acc[i][2]; o.w = acc[i][3];
        *(float4*)&pr[(size_t)(m0 + ty * 4 + i) * 384 + n0 + tx * 4] = o;
    }
}

// ---------------- K6: sum split-K partials + bias ----------------
__global__ __launch_bounds__(256) void k_fin(
    const float* __restrict__ pout, const float* __restrict__ bo, float* __restrict__ out)
{
    int idx = blockIdx.x * 256 + threadIdx.x;
    float4 a = *(const float4*)&pout[(size_t)idx * 4];
    float4 b = *(const float4*)&pout[393216 + (size_t)idx * 4];
    float4 c = *(const float4*)&pout[786432 + (size_t)idx * 4];
    float4 d = *(const float4*)&pout[1179648 + (size_t)idx * 4];
    float4 bias = *(const float4*)&bo[(idx % 96) * 4];
    float4 o;
    o.x = a.x + b.x + c.x + d.x + bias.x;
    o.y = a.y + b.y + c.y + d.y + bias.y;
    o.z = a.z + b.z + c.z + d.z + bias.z;
    o.w = a.w + b.w + c.w + d.w + bias.w;
    *(float4*)&out[(size_t)idx * 4] = o;
}

extern "C" void kernel_launch(void* const* d_in, const int* in_sizes, int n_in,
                              void* d_out, int out_size, void* d_ws, size_t ws_size,
                              hipStream_t stream) {
    const float* in1   = (const float*)d_in[0];
    const float* x2d   = (const float*)d_in[1];
    const float* mask  = (const float*)d_in[2];
    const float* rotm  = (const float*)d_in[3];
    const float* trans = (const float*)d_in[4];
    const float* wq    = (const float*)d_in[5];
    const float* bq    = (const float*)d_in[6];
    const float* wkv   = (const float*)d_in[7];
    const float* bkv   = (const float*)d_in[8];
    const float* wqp   = (const float*)d_in[9];
    const float* bqp   = (const float*)d_in[10];
    const float* wkvp  = (const float*)d_in[11];
    const float* bkvp  = (const float*)d_in[12];
    const float* w2d   = (const float*)d_in[13];
    const float* b2d   = (const float*)d_in[14];
    const float* tpw   = (const float*)d_in[15];
    const float* wo    = (const float*)d_in[16];
    const float* bo    = (const float*)d_in[17];
    float* out = (float*)d_out;

    float* ws = (float*)d_ws;
    float* yraw   = ws;                    // 1,179,648
    float* qp_arr = yraw + 1179648;        //   147,456
    float* kpack  = qp_arr + 147456;       //   360,448
    float* vpack  = kpack + 360448;        //   491,520
    float* sq_arr = vpack + 491520;        //    12,288
    float* fin    = sq_arr + 12288;        // 2,162,688
    float* pout   = fin + 2162688;         // 1,572,864

    hipLaunchKernelGGL(k_gemm1, dim3(16, 18), dim3(256), 0, stream,
        in1, wq, bq, wkv, bkv, wqp, bqp, wkvp, bkvp, yraw);
    hipLaunchKernelGGL(k_rot, dim3(256), dim3(256), 0, stream,
        yraw, rotm, trans, qp_arr, kpack, vpack, sq_arr);
    hipLaunchKernelGGL(k_attn5, dim3(1024), dim3(256), 0, stream,
        x2d, mask, w2d, b2d, tpw, yraw, qp_arr, kpack, vpack, sq_arr, rotm, trans, fin);
    hipLaunchKernelGGL(k_out, dim3(16, 6, 4), dim3(256), 0, stream, fin, wo, pout);
    hipLaunchKernelGGL(k_fin, dim3(384), dim3(256), 0, stream, pout, bo, out);
}

// Round 8
// 441.923 us; speedup vs baseline: 6.4351x; 1.4898x over previous
//
#include <hip/hip_runtime.h>
#include <math.h>

#define NN_ 1024
#define DOUT_ 2112
#define NOUT_ 384

// ---------------- K1: yraw[1024][1152] = in1 @ [wq|wkv|wqp|wkvp] + bias ----------------
__global__ __launch_bounds__(256) void k_gemm1(
    const float* __restrict__ in1,
    const float* __restrict__ wq, const float* __restrict__ bq,
    const float* __restrict__ wkv, const float* __restrict__ bkv,
    const float* __restrict__ wqp, const float* __restrict__ bqp,
    const float* __restrict__ wkvp, const float* __restrict__ bkvp,
    float* __restrict__ yraw)
{
    __shared__ float a_l[64 * 36];
    __shared__ float b_l[32 * 68];
    const int t = threadIdx.x;
    const int m0 = blockIdx.x * 64, j0 = blockIdx.y * 64;
    const int tx = t & 15, ty = t >> 4;
    float acc[4][4] = {};
    for (int k0 = 0; k0 < 384; k0 += 32) {
        #pragma unroll
        for (int e = 0; e < 2; ++e) {
            int idx = t + 256 * e;
            int r = idx >> 3, c4 = (idx & 7) * 4;
            *(float4*)&a_l[r * 36 + c4] = *(const float4*)&in1[(size_t)(m0 + r) * 384 + k0 + c4];
        }
        #pragma unroll
        for (int e = 0; e < 2; ++e) {
            int idx = t + 256 * e;
            int r = idx >> 4, c4 = (idx & 15) * 4;
            int j = j0 + c4;
            const float* w; int ncol, jj;
            if (j < 192)      { w = wq;   ncol = 192; jj = j; }
            else if (j < 576) { w = wkv;  ncol = 384; jj = j - 192; }
            else if (j < 720) { w = wqp;  ncol = 144; jj = j - 576; }
            else              { w = wkvp; ncol = 432; jj = j - 720; }
            *(float4*)&b_l[r * 68 + c4] = *(const float4*)&w[(size_t)(k0 + r) * ncol + jj];
        }
        __syncthreads();
        #pragma unroll 8
        for (int k = 0; k < 32; ++k) {
            float4 bv = *(const float4*)&b_l[k * 68 + tx * 4];
            #pragma unroll
            for (int i = 0; i < 4; ++i) {
                float av = a_l[(ty * 4 + i) * 36 + k];
                acc[i][0] += av * bv.x; acc[i][1] += av * bv.y;
                acc[i][2] += av * bv.z; acc[i][3] += av * bv.w;
            }
        }
        __syncthreads();
    }
    int j = j0 + tx * 4;
    float4 bias;
    {
        const float* b; int jj;
        if (j < 192)      { b = bq;   jj = j; }
        else if (j < 576) { b = bkv;  jj = j - 192; }
        else if (j < 720) { b = bqp;  jj = j - 576; }
        else              { b = bkvp; jj = j - 720; }
        bias = *(const float4*)&b[jj];
    }
    #pragma unroll
    for (int i = 0; i < 4; ++i) {
        float4 o;
        o.x = acc[i][0] + bias.x; o.y = acc[i][1] + bias.y;
        o.z = acc[i][2] + bias.z; o.w = acc[i][3] + bias.w;
        *(float4*)&yraw[(size_t)(m0 + ty * 4 + i) * 1152 + j] = o;
    }
}

// ---------------- K2: rotations + packing (K transposed for coalesced logits loads) ----
// kpackT4: element (j, m) at (j>>2)*4096 + 4*m + (j&3), j in [0,352):
//   j 0..191   = ks (h*16+s)
//   j 192..335 = kp (a*48 + h*4 + p)
// skT[h*1024 + m] = sk
// vpack[m][480]: [0:192 vs(h*16+s)] [192:480 vp(a*96+h*8+p)]  (row layout, coalesced in resF)
__global__ __launch_bounds__(256) void k_rot(
    const float* __restrict__ yraw, const float* __restrict__ rotm, const float* __restrict__ trans,
    float* __restrict__ qp_arr, float* __restrict__ kpackT4, float* __restrict__ vpack,
    float* __restrict__ sq_arr, float* __restrict__ skT)
{
    __shared__ float rt_l[4][12];
    const int t = threadIdx.x;
    const int n0 = blockIdx.x * 4;
    if (t < 48) {
        int n_ = t / 12, i = t % 12;
        rt_l[n_][i] = (i < 9) ? rotm[(n0 + n_) * 9 + i] : trans[(n0 + n_) * 3 + (i - 9)];
    }
    __syncthreads();
    const int n_ = t >> 6, l = t & 63;
    const int n = n0 + n_;
    const float* y = yraw + (size_t)n * 1152;
    const float* R = rt_l[n_];
    #pragma unroll
    for (int jj = 0; jj < 9; ++jj) {
        int o = l + 64 * jj;
        if (o < 144) {
            int a = o / 48, kk = o % 48;
            float v = R[9 + a] + R[a*3+0] * y[576 + kk] + R[a*3+1] * y[576 + 48 + kk] + R[a*3+2] * y[576 + 96 + kk];
            qp_arr[(size_t)n * 144 + o] = v;
        } else if (o < 288) {
            int o2 = o - 144;
            int a = o2 / 48, r2 = o2 % 48;
            int kk = (r2 >> 2) * 12 + (r2 & 3);
            float v = R[9 + a] + R[a*3+0] * y[720 + kk] + R[a*3+1] * y[720 + 144 + kk] + R[a*3+2] * y[720 + 288 + kk];
            int j = 192 + o2;
            kpackT4[(size_t)(j >> 2) * 4096 + 4 * n + (j & 3)] = v;
        } else {
            int o3 = o - 288;
            int a = o3 / 96, r2 = o3 % 96;
            int kk = (r2 >> 3) * 12 + 4 + (r2 & 7);
            float v = R[9 + a] + R[a*3+0] * y[720 + kk] + R[a*3+1] * y[720 + 144 + kk] + R[a*3+2] * y[720 + 288 + kk];
            vpack[(size_t)n * 480 + 192 + o3] = v;
        }
    }
    #pragma unroll
    for (int jj = 0; jj < 3; ++jj) {
        int o = l + 64 * jj;  // j = o in 0..191
        int h = o >> 4, r2 = o & 15;
        kpackT4[(size_t)(o >> 2) * 4096 + 4 * n + (o & 3)] = y[192 + h * 32 + r2];
        vpack[(size_t)n * 480 + o] = y[192 + h * 32 + 16 + r2];
    }
    if (l < 24) {
        int which = l / 12, h = l % 12;
        int base = (which == 0) ? 576 : 720;
        int stride = (which == 0) ? 48 : 144;
        float s = 0.f;
        #pragma unroll
        for (int a = 0; a < 3; ++a) {
            #pragma unroll
            for (int p = 0; p < 4; ++p) {
                int kk = (which == 0) ? (h * 4 + p) : (h * 12 + p);
                float v = R[9 + a] + R[a*3+0] * y[base + kk] + R[a*3+1] * y[base + stride + kk] + R[a*3+2] * y[base + 2 * stride + kk];
                s += v * v;
            }
        }
        if (which == 0) sq_arr[(size_t)n * 12 + h] = s;
        else            skT[(size_t)h * 1024 + n] = s;
    }
}

// ---------------- K3: fused flash IPA, one n per block, MT=64, 256 threads ----------------
// plain __launch_bounds__(256): any min-waves hint caps VGPR at 64 and spills GBs (r3-5).
// x_l stored as bf16 (round-half-up): LDS 49.7K -> ~33K => 4 blocks/CU, no 3+1 tail.
__global__ __launch_bounds__(256) void k_attn6(
    const float* __restrict__ x2d, const float* __restrict__ mask,
    const float* __restrict__ w2d, const float* __restrict__ b2d, const float* __restrict__ tpw,
    const float* __restrict__ yraw, const float* __restrict__ qp_arr,
    const float* __restrict__ kpackT4, const float* __restrict__ vpack,
    const float* __restrict__ sq_arr, const float* __restrict__ skT,
    const float* __restrict__ rotm, const float* __restrict__ trans,
    float* __restrict__ fin)
{
    __shared__ unsigned short x_l[64][136];  // 17.4 KB bf16; stride 136 keeps 16B-aligned rows
    __shared__ float w2r_l[4 * 388];         // 6.2 KB, per-q4 blocks -> distinct bank-quads
    __shared__ float tl[12][68];             // 3.3 KB
    __shared__ float at2_l[64][13];          // 3.3 KB
    __shared__ float qs_l[192], qp_l[144];
    __shared__ float sq_l[12], pw_l[12], b2_l[12];
    __shared__ float rmax_l[12], rsum_l[12], alph_l[12];
    __shared__ float rt_l[12];
    __shared__ float pg_l[288];

    const int t = threadIdx.x;
    const int n = blockIdx.x;

    const int sm = t >> 2, q4 = t & 3;     // stage: m (64), c-quarter (32 c)
    const int m3 = t & 63, hg = t >> 6;    // logits: lane=m, wave=h-trio
    const int cR = t & 63, hgR = t >> 6;   // res2d: c-pair (2cR,2cR+1), h-trio
    const int jF = 2 * t;                  // resF: j pair (t<240)
    const int hF = (jF < 192) ? (jF >> 4) : (((jF - 192) % 96) >> 3);

    float acc[3][2] = {};
    float accF0 = 0.f, accF1 = 0.f;
    float4 xpf[8];

    // ---- prologue ----
    for (int i = t; i < 1536; i += 256) {
        int q = i / 384, r = i % 384;
        int f = r / 48, r2 = r % 48;
        int h = r2 >> 2, ii = r2 & 3;
        int c = q * 32 + f * 4 + ii;
        w2r_l[q * 388 + f * 48 + h * 4 + ii] = w2d[c * 12 + h];
    }
    if (t < 192) qs_l[t] = yraw[(size_t)n * 1152 + t];
    if (t < 144) qp_l[t] = qp_arr[(size_t)n * 144 + t];
    if (t < 12) {
        sq_l[t] = sq_arr[(size_t)n * 12 + t];
        pw_l[t] = 0.13608276348795434f * log1pf(__expf(tpw[t]));
        b2_l[t] = b2d[t];
        rmax_l[t] = -3.0e38f; rsum_l[t] = 0.f;
        rt_l[t] = (t < 9) ? rotm[n * 9 + t] : trans[n * 3 + (t - 9)];
    }
    const float maskn = mask[n];

    {
        const float* xr = x2d + ((size_t)n * NN_ + sm) * 128 + q4 * 32;
        #pragma unroll
        for (int f = 0; f < 8; ++f) xpf[f] = *(const float4*)&xr[4 * f];
    }
    __syncthreads();

    for (int mt = 0; mt < 16; ++mt) {
        const int m0 = mt * 64;
        // ===== STAGE: pack xpf -> bf16 x_l, compute at2 partials from fp32 registers =====
        #pragma unroll
        for (int f = 0; f < 8; ++f) {
            unsigned int lo = ((__float_as_uint(xpf[f].x) + 0x8000u) >> 16)
                            | ((__float_as_uint(xpf[f].y) + 0x8000u) & 0xFFFF0000u);
            unsigned int hi = ((__float_as_uint(xpf[f].z) + 0x8000u) >> 16)
                            | ((__float_as_uint(xpf[f].w) + 0x8000u) & 0xFFFF0000u);
            *(uint2*)&x_l[sm][q4 * 32 + 4 * f] = make_uint2(lo, hi);
        }
        {
            float at2[12];
            #pragma unroll
            for (int h = 0; h < 12; ++h) at2[h] = 0.f;
            #pragma unroll
            for (int f = 0; f < 8; ++f) {
                #pragma unroll
                for (int h = 0; h < 12; ++h) {
                    float4 wv = *(const float4*)&w2r_l[q4 * 388 + f * 48 + h * 4];
                    at2[h] += xpf[f].x * wv.x + xpf[f].y * wv.y + xpf[f].z * wv.z + xpf[f].w * wv.w;
                }
            }
            #pragma unroll
            for (int h = 0; h < 12; ++h) {
                at2[h] += __shfl_xor(at2[h], 1);
                at2[h] += __shfl_xor(at2[h], 2);
            }
            if (q4 == 0) {
                #pragma unroll
                for (int h = 0; h < 12; ++h) at2_l[sm][h] = at2[h];
            }
        }
        __syncthreads();   // (1) x_l/at2_l ready

        // ===== LOGITS + wave-internal online softmax (coalesced kpackT4 loads) =====
        {
            int m1 = (mt + 1 == 16) ? 0 : (m0 + 64);
            const float* xr = x2d + ((size_t)n * NN_ + m1 + sm) * 128 + q4 * 32;
            #pragma unroll
            for (int f = 0; f < 8; ++f) xpf[f] = *(const float4*)&xr[4 * f];
        }
        {
            const int mg = m0 + m3;
            const float* kb = kpackT4 + 4 * (size_t)mg;   // lane-coalesced: element (j,mg) = kb[(j>>2)*4096 + (j&3)]
            const float mko = 100000.0f * (1.0f - maskn * mask[mg]);
            #pragma unroll
            for (int e = 0; e < 3; ++e) {
                const int h = hg * 3 + e;
                float4 k0 = *(const float4*)&kb[(size_t)(h * 4 + 0) * 4096];
                float4 k1 = *(const float4*)&kb[(size_t)(h * 4 + 1) * 4096];
                float4 k2 = *(const float4*)&kb[(size_t)(h * 4 + 2) * 4096];
                float4 k3 = *(const float4*)&kb[(size_t)(h * 4 + 3) * 4096];
                float4 p0 = *(const float4*)&kb[(size_t)(48 + h) * 4096];
                float4 p1 = *(const float4*)&kb[(size_t)(60 + h) * 4096];
                float4 p2 = *(const float4*)&kb[(size_t)(72 + h) * 4096];
                float skm = skT[(size_t)h * 1024 + mg];
                const float4* qsn = (const float4*)&qs_l[h * 16];
                float dqs = qsn[0].x*k0.x + qsn[0].y*k0.y + qsn[0].z*k0.z + qsn[0].w*k0.w
                          + qsn[1].x*k1.x + qsn[1].y*k1.y + qsn[1].z*k1.z + qsn[1].w*k1.w
                          + qsn[2].x*k2.x + qsn[2].y*k2.y + qsn[2].z*k2.z + qsn[2].w*k2.w
                          + qsn[3].x*k3.x + qsn[3].y*k3.y + qsn[3].z*k3.z + qsn[3].w*k3.w;
                float4 qA = *(const float4*)&qp_l[h * 4];
                float4 qB = *(const float4*)&qp_l[48 + h * 4];
                float4 qC = *(const float4*)&qp_l[96 + h * 4];
                float qk = qA.x*p0.x + qA.y*p0.y + qA.z*p0.z + qA.w*p0.w
                         + qB.x*p1.x + qB.y*p1.y + qB.z*p1.z + qB.w*p1.w
                         + qC.x*p2.x + qC.y*p2.y + qC.z*p2.z + qC.w*p2.w;
                float pwh = pw_l[h];
                float lg = 0.14433756729740643f * dqs
                         + pwh * qk - 0.5f * pwh * (sq_l[h] + skm)
                         + 0.57735026918962576f * (at2_l[m3][h] + b2_l[h])
                         - mko;
                float tm = lg;
                tm = fmaxf(tm, __shfl_xor(tm, 1));
                tm = fmaxf(tm, __shfl_xor(tm, 2));
                tm = fmaxf(tm, __shfl_xor(tm, 4));
                tm = fmaxf(tm, __shfl_xor(tm, 8));
                tm = fmaxf(tm, __shfl_xor(tm, 16));
                tm = fmaxf(tm, __shfl_xor(tm, 32));
                float om = rmax_l[h];
                float nm = fmaxf(om, tm);
                float p = __expf(lg - nm);
                tl[h][m3] = p;
                float ps = p;
                ps += __shfl_xor(ps, 1);
                ps += __shfl_xor(ps, 2);
                ps += __shfl_xor(ps, 4);
                ps += __shfl_xor(ps, 8);
                ps += __shfl_xor(ps, 16);
                ps += __shfl_xor(ps, 32);
                if (m3 == 0) {
                    float al = __expf(om - nm);
                    rmax_l[h] = nm;
                    alph_l[h] = al;
                    rsum_l[h] = rsum_l[h] * al + ps;
                }
            }
        }
        __syncthreads();   // (2) p/alph ready

        // ===== ACCUM: res2d (bf16 LDS, adjacent c-pair per thread) + resF (L2) =====
        {
            const int hb = hgR * 3;
            float al0 = alph_l[hb], al1 = alph_l[hb + 1], al2 = alph_l[hb + 2];
            acc[0][0] *= al0; acc[0][1] *= al0;
            acc[1][0] *= al1; acc[1][1] *= al1;
            acc[2][0] *= al2; acc[2][1] *= al2;
            #pragma unroll 4
            for (int mm = 0; mm < 64; mm += 4) {
                float4 p0 = *(const float4*)&tl[hb + 0][mm];
                float4 p1 = *(const float4*)&tl[hb + 1][mm];
                float4 p2 = *(const float4*)&tl[hb + 2][mm];
                float pa0[4] = {p0.x, p0.y, p0.z, p0.w};
                float pa1[4] = {p1.x, p1.y, p1.z, p1.w};
                float pa2[4] = {p2.x, p2.y, p2.z, p2.w};
                #pragma unroll
                for (int q = 0; q < 4; ++q) {
                    unsigned int ux = *(const unsigned int*)&x_l[mm + q][2 * cR];
                    float xa = __uint_as_float(ux << 16);
                    float xb = __uint_as_float(ux & 0xFFFF0000u);
                    acc[0][0] = fmaf(pa0[q], xa, acc[0][0]); acc[0][1] = fmaf(pa0[q], xb, acc[0][1]);
                    acc[1][0] = fmaf(pa1[q], xa, acc[1][0]); acc[1][1] = fmaf(pa1[q], xb, acc[1][1]);
                    acc[2][0] = fmaf(pa2[q], xa, acc[2][0]); acc[2][1] = fmaf(pa2[q], xb, acc[2][1]);
                }
            }
        }
        if (t < 240) {
            float alf = alph_l[hF];
            accF0 *= alf; accF1 *= alf;
            const float* vb = vpack + (size_t)m0 * 480 + jF;
            #pragma unroll 4
            for (int mm = 0; mm < 64; mm += 4) {
                float4 p = *(const float4*)&tl[hF][mm];
                float2 v0 = *(const float2*)&vb[(size_t)(mm + 0) * 480];
                float2 v1 = *(const float2*)&vb[(size_t)(mm + 1) * 480];
                float2 v2 = *(const float2*)&vb[(size_t)(mm + 2) * 480];
                float2 v3 = *(const float2*)&vb[(size_t)(mm + 3) * 480];
                accF0 += p.x * v0.x + p.y * v1.x + p.z * v2.x + p.w * v3.x;
                accF1 += p.x * v0.y + p.y * v1.y + p.z * v2.y + p.w * v3.y;
            }
        }
        __syncthreads();   // (3) protect x_l/tl/at2_l for next stage
    }

    // ================= epilogue =================
    {
        const int hb = hgR * 3;
        #pragma unroll
        for (int e = 0; e < 3; ++e) {
            float inv = 1.f / rsum_l[hb + e];
            float2 o; o.x = acc[e][0] * inv; o.y = acc[e][1] * inv;
            *(float2*)&fin[(size_t)n * DOUT_ + 576 + (size_t)(hb + e) * 128 + 2 * cR] = o;
        }
    }
    if (t < 240) {
        float inv = 1.f / rsum_l[hF];
        float vA = accF0 * inv, vB = accF1 * inv;
        if (jF < 192) {
            fin[(size_t)n * DOUT_ + jF]     = vA;
            fin[(size_t)n * DOUT_ + jF + 1] = vB;
        } else {
            pg_l[jF - 192] = vA;
            pg_l[jF - 191] = vB;
        }
    }
    __syncthreads();
    if (t < 96) {
        const int k = t;
        float c0 = pg_l[k]       - rt_l[9];
        float c1 = pg_l[96 + k]  - rt_l[10];
        float c2 = pg_l[192 + k] - rt_l[11];
        float r0 = rt_l[0] * c0 + rt_l[3] * c1 + rt_l[6] * c2;
        float r1 = rt_l[1] * c0 + rt_l[4] * c1 + rt_l[7] * c2;
        float r2 = rt_l[2] * c0 + rt_l[5] * c1 + rt_l[8] * c2;
        size_t base = (size_t)n * DOUT_;
        fin[base + 192 + k] = r0;
        fin[base + 288 + k] = r1;
        fin[base + 384 + k] = r2;
        fin[base + 480 + k] = sqrtf(1e-8f + r0 * r0 + r1 * r1 + r2 * r2);
    }
}

// ---------------- K5: out partials, split-K over 4 chunks of 528 ----------------
__global__ __launch_bounds__(256) void k_out(
    const float* __restrict__ fin, const float* __restrict__ wo,
    float* __restrict__ pout)
{
    __shared__ float a_l[64 * 52];
    __shared__ float b_l[48 * 68];
    const int t = threadIdx.x;
    const int m0 = blockIdx.x * 64, n0 = blockIdx.y * 64, kc = blockIdx.z;
    const int tx = t & 15, ty = t >> 4;
    float acc[4][4] = {};
    for (int k0 = kc * 528; k0 < kc * 528 + 528; k0 += 48) {
        #pragma unroll
        for (int e = 0; e < 3; ++e) {
            int idx = t + 256 * e;
            int r = idx / 12, c4 = (idx % 12) * 4;
            *(float4*)&a_l[r * 52 + c4] = *(const float4*)&fin[(size_t)(m0 + r) * DOUT_ + k0 + c4];
        }
        #pragma unroll
        for (int e = 0; e < 3; ++e) {
            int idx = t + 256 * e;
            int r = idx >> 4, c4 = (idx & 15) * 4;
            *(float4*)&b_l[r * 68 + c4] = *(const float4*)&wo[(size_t)(k0 + r) * 384 + n0 + c4];
        }
        __syncthreads();
        #pragma unroll 4
        for (int k = 0; k < 48; ++k) {
            float4 bv = *(const float4*)&b_l[k * 68 + tx * 4];
            #pragma unroll
            for (int i = 0; i < 4; ++i) {
                float av = a_l[(ty * 4 + i) * 52 + k];
                acc[i][0] += av * bv.x; acc[i][1] += av * bv.y;
                acc[i][2] += av * bv.z; acc[i][3] += av * bv.w;
            }
        }
        __syncthreads();
    }
    float* pr = pout + (size_t)kc * 393216;
    #pragma unroll
    for (int i = 0; i < 4; ++i) {
        float4 o;
        o.x = acc[i][0]; o.y = acc[i][1]; o.z = acc[i][2]; o.w = acc[i][3];
        *(float4*)&pr[(size_t)(m0 + ty * 4 + i) * 384 + n0 + tx * 4] = o;
    }
}

// ---------------- K6: sum split-K partials + bias ----------------
__global__ __launch_bounds__(256) void k_fin(
    const float* __restrict__ pout, const float* __restrict__ bo, float* __restrict__ out)
{
    int idx = blockIdx.x * 256 + threadIdx.x;
    float4 a = *(const float4*)&pout[(size_t)idx * 4];
    float4 b = *(const float4*)&pout[393216 + (size_t)idx * 4];
    float4 c = *(const float4*)&pout[786432 + (size_t)idx * 4];
    float4 d = *(const float4*)&pout[1179648 + (size_t)idx * 4];
    float4 bias = *(const float4*)&bo[(idx % 96) * 4];
    float4 o;
    o.x = a.x + b.x + c.x + d.x + bias.x;
    o.y = a.y + b.y + c.y + d.y + bias.y;
    o.z = a.z + b.z + c.z + d.z + bias.z;
    o.w = a.w + b.w + c.w + d.w + bias.w;
    *(float4*)&out[(size_t)idx * 4] = o;
}

extern "C" void kernel_launch(void* const* d_in, const int* in_sizes, int n_in,
                              void* d_out, int out_size, void* d_ws, size_t ws_size,
                              hipStream_t stream) {
    const float* in1   = (const float*)d_in[0];
    const float* x2d   = (const float*)d_in[1];
    const float* mask  = (const float*)d_in[2];
    const float* rotm  = (const float*)d_in[3];
    const float* trans = (const float*)d_in[4];
    const float* wq    = (const float*)d_in[5];
    const float* bq    = (const float*)d_in[6];
    const float* wkv   = (const float*)d_in[7];
    const float* bkv   = (const float*)d_in[8];
    const float* wqp   = (const float*)d_in[9];
    const float* bqp   = (const float*)d_in[10];
    const float* wkvp  = (const float*)d_in[11];
    const float* bkvp  = (const float*)d_in[12];
    const float* w2d   = (const float*)d_in[13];
    const float* b2d   = (const float*)d_in[14];
    const float* tpw   = (const float*)d_in[15];
    const float* wo    = (const float*)d_in[16];
    const float* bo    = (const float*)d_in[17];
    float* out = (float*)d_out;

    float* ws = (float*)d_ws;
    float* yraw    = ws;                    // 1,179,648
    float* qp_arr  = yraw + 1179648;        //   147,456
    float* kpackT4 = qp_arr + 147456;       //   360,448 (88 j-groups x 1024 m x 4)
    float* vpack   = kpackT4 + 360448;      //   491,520
    float* sq_arr  = vpack + 491520;        //    12,288
    float* fin     = sq_arr + 12288;        // 2,162,688
    float* pout    = fin + 2162688;         // 1,572,864
    float* skT     = pout + 1572864;        //    12,288

    hipLaunchKernelGGL(k_gemm1, dim3(16, 18), dim3(256), 0, stream,
        in1, wq, bq, wkv, bkv, wqp, bqp, wkvp, bkvp, yraw);
    hipLaunchKernelGGL(k_rot, dim3(256), dim3(256), 0, stream,
        yraw, rotm, trans, qp_arr, kpackT4, vpack, sq_arr, skT);
    hipLaunchKernelGGL(k_attn6, dim3(1024), dim3(256), 0, stream,
        x2d, mask, w2d, b2d, tpw, yraw, qp_arr, kpackT4, vpack, sq_arr, skT, rotm, trans, fin);
    hipLaunchKernelGGL(k_out, dim3(16, 6, 4), dim3(256), 0, stream, fin, wo, pout);
    hipLaunchKernelGGL(k_fin, dim3(384), dim3(256), 0, stream, pout, bo, out);
}

// Round 9
// 401.965 us; speedup vs baseline: 7.0747x; 1.0994x over previous
//
#include <hip/hip_runtime.h>
#include <math.h>

#define NN_ 1024
#define DOUT_ 2112
#define NOUT_ 384

using bf16x8_t = __attribute__((ext_vector_type(8))) short;
using f32x4_t  = __attribute__((ext_vector_type(4))) float;

// ---------------- K1: yraw[1024][1152] = in1 @ [wq|wkv|wqp|wkvp] + bias ----------------
__global__ __launch_bounds__(256) void k_gemm1(
    const float* __restrict__ in1,
    const float* __restrict__ wq, const float* __restrict__ bq,
    const float* __restrict__ wkv, const float* __restrict__ bkv,
    const float* __restrict__ wqp, const float* __restrict__ bqp,
    const float* __restrict__ wkvp, const float* __restrict__ bkvp,
    float* __restrict__ yraw)
{
    __shared__ float a_l[64 * 36];
    __shared__ float b_l[32 * 68];
    const int t = threadIdx.x;
    const int m0 = blockIdx.x * 64, j0 = blockIdx.y * 64;
    const int tx = t & 15, ty = t >> 4;
    float acc[4][4] = {};
    for (int k0 = 0; k0 < 384; k0 += 32) {
        #pragma unroll
        for (int e = 0; e < 2; ++e) {
            int idx = t + 256 * e;
            int r = idx >> 3, c4 = (idx & 7) * 4;
            *(float4*)&a_l[r * 36 + c4] = *(const float4*)&in1[(size_t)(m0 + r) * 384 + k0 + c4];
        }
        #pragma unroll
        for (int e = 0; e < 2; ++e) {
            int idx = t + 256 * e;
            int r = idx >> 4, c4 = (idx & 15) * 4;
            int j = j0 + c4;
            const float* w; int ncol, jj;
            if (j < 192)      { w = wq;   ncol = 192; jj = j; }
            else if (j < 576) { w = wkv;  ncol = 384; jj = j - 192; }
            else if (j < 720) { w = wqp;  ncol = 144; jj = j - 576; }
            else              { w = wkvp; ncol = 432; jj = j - 720; }
            *(float4*)&b_l[r * 68 + c4] = *(const float4*)&w[(size_t)(k0 + r) * ncol + jj];
        }
        __syncthreads();
        #pragma unroll 8
        for (int k = 0; k < 32; ++k) {
            float4 bv = *(const float4*)&b_l[k * 68 + tx * 4];
            #pragma unroll
            for (int i = 0; i < 4; ++i) {
                float av = a_l[(ty * 4 + i) * 36 + k];
                acc[i][0] += av * bv.x; acc[i][1] += av * bv.y;
                acc[i][2] += av * bv.z; acc[i][3] += av * bv.w;
            }
        }
        __syncthreads();
    }
    int j = j0 + tx * 4;
    float4 bias;
    {
        const float* b; int jj;
        if (j < 192)      { b = bq;   jj = j; }
        else if (j < 576) { b = bkv;  jj = j - 192; }
        else if (j < 720) { b = bqp;  jj = j - 576; }
        else              { b = bkvp; jj = j - 720; }
        bias = *(const float4*)&b[jj];
    }
    #pragma unroll
    for (int i = 0; i < 4; ++i) {
        float4 o;
        o.x = acc[i][0] + bias.x; o.y = acc[i][1] + bias.y;
        o.z = acc[i][2] + bias.z; o.w = acc[i][3] + bias.w;
        *(float4*)&yraw[(size_t)(m0 + ty * 4 + i) * 1152 + j] = o;
    }
}

// ---------------- K2: rotations + packing (K transposed for coalesced logits loads) ----
__global__ __launch_bounds__(256) void k_rot(
    const float* __restrict__ yraw, const float* __restrict__ rotm, const float* __restrict__ trans,
    float* __restrict__ qp_arr, float* __restrict__ kpackT4, float* __restrict__ vpack,
    float* __restrict__ sq_arr, float* __restrict__ skT)
{
    __shared__ float rt_l[4][12];
    const int t = threadIdx.x;
    const int n0 = blockIdx.x * 4;
    if (t < 48) {
        int n_ = t / 12, i = t % 12;
        rt_l[n_][i] = (i < 9) ? rotm[(n0 + n_) * 9 + i] : trans[(n0 + n_) * 3 + (i - 9)];
    }
    __syncthreads();
    const int n_ = t >> 6, l = t & 63;
    const int n = n0 + n_;
    const float* y = yraw + (size_t)n * 1152;
    const float* R = rt_l[n_];
    #pragma unroll
    for (int jj = 0; jj < 9; ++jj) {
        int o = l + 64 * jj;
        if (o < 144) {
            int a = o / 48, kk = o % 48;
            float v = R[9 + a] + R[a*3+0] * y[576 + kk] + R[a*3+1] * y[576 + 48 + kk] + R[a*3+2] * y[576 + 96 + kk];
            qp_arr[(size_t)n * 144 + o] = v;
        } else if (o < 288) {
            int o2 = o - 144;
            int a = o2 / 48, r2 = o2 % 48;
            int kk = (r2 >> 2) * 12 + (r2 & 3);
            float v = R[9 + a] + R[a*3+0] * y[720 + kk] + R[a*3+1] * y[720 + 144 + kk] + R[a*3+2] * y[720 + 288 + kk];
            int j = 192 + o2;
            kpackT4[(size_t)(j >> 2) * 4096 + 4 * n + (j & 3)] = v;
        } else {
            int o3 = o - 288;
            int a = o3 / 96, r2 = o3 % 96;
            int kk = (r2 >> 3) * 12 + 4 + (r2 & 7);
            float v = R[9 + a] + R[a*3+0] * y[720 + kk] + R[a*3+1] * y[720 + 144 + kk] + R[a*3+2] * y[720 + 288 + kk];
            vpack[(size_t)n * 480 + 192 + o3] = v;
        }
    }
    #pragma unroll
    for (int jj = 0; jj < 3; ++jj) {
        int o = l + 64 * jj;
        int h = o >> 4, r2 = o & 15;
        kpackT4[(size_t)(o >> 2) * 4096 + 4 * n + (o & 3)] = y[192 + h * 32 + r2];
        vpack[(size_t)n * 480 + o] = y[192 + h * 32 + 16 + r2];
    }
    if (l < 24) {
        int which = l / 12, h = l % 12;
        int base = (which == 0) ? 576 : 720;
        int stride = (which == 0) ? 48 : 144;
        float s = 0.f;
        #pragma unroll
        for (int a = 0; a < 3; ++a) {
            #pragma unroll
            for (int p = 0; p < 4; ++p) {
                int kk = (which == 0) ? (h * 4 + p) : (h * 12 + p);
                float v = R[9 + a] + R[a*3+0] * y[base + kk] + R[a*3+1] * y[base + stride + kk] + R[a*3+2] * y[base + 2 * stride + kk];
                s += v * v;
            }
        }
        if (which == 0) sq_arr[(size_t)n * 12 + h] = s;
        else            skT[(size_t)h * 1024 + n] = s;
    }
}

// ---------------- K3: fused flash IPA, one n per block, MT=64, 256 threads, MFMA res2d ----
// plain __launch_bounds__(256): any min-waves hint caps VGPR at 64 and spills GBs (r3-5).
// res2d = P(16x64) x X(64x128) per tile via mfma_f32_16x16x32_bf16:
//   A-frag: lane holds A[row=lane&15][k=(lane>>4)*8+j] -> tlb[h][m] b128 reads
//   B-frag: lane holds B[k=(lane>>4)*8+j][col=lane&15] -> x_lT[c][m] b128 reads
//   D: col=lane&15 (=c), row=(lane>>4)*4+reg (=h)   [guide m89]
__global__ __launch_bounds__(256) void k_attn7(
    const float* __restrict__ x2d, const float* __restrict__ mask,
    const float* __restrict__ w2d, const float* __restrict__ b2d, const float* __restrict__ tpw,
    const float* __restrict__ yraw, const float* __restrict__ qp_arr,
    const float* __restrict__ kpackT4, const float* __restrict__ vpack,
    const float* __restrict__ sq_arr, const float* __restrict__ skT,
    const float* __restrict__ rotm, const float* __restrict__ trans,
    float* __restrict__ fin)
{
    __shared__ unsigned short x_lT[128][72];  // 18.4 KB bf16 [c][m]; 144B rows: 16B-aligned frags, 2-way banks
    __shared__ unsigned short tlb[16][72];    // 2.3 KB bf16 P [h][m]; rows 12-15 feed unused D rows
    __shared__ float w2r_l[4 * 388];          // per-q4 blocks, c-interleaved layout
    __shared__ float at2_l[64][13];
    __shared__ float qs_l[192], qp_l[144];
    __shared__ float sq_l[12], pw_l[12], b2_l[12];
    __shared__ float rmax_l[12], rsum_l[16], alph_l[16];
    __shared__ float rt_l[12];
    __shared__ float pg_l[288];

    const int t = threadIdx.x;
    const int n = blockIdx.x;

    const int sm = t >> 2, q4 = t & 3;     // stage/at2: m, c-interleave quarter
    const int m3 = t & 63, hg = t >> 6;    // logits: lane=m, wave=h-trio
    const int wv = t >> 6, ln = t & 63;    // mfma: wave=c-pair-of-16-tiles, lane
    const int rowB = (ln >> 4) * 4;        // D rows this lane holds
    const int jF = 2 * t;                  // resF: j pair (t<240)
    const int hF = (jF < 192) ? (jF >> 4) : (((jF - 192) % 96) >> 3);

    f32x4_t accM[2] = {{0.f, 0.f, 0.f, 0.f}, {0.f, 0.f, 0.f, 0.f}};
    float accF0 = 0.f, accF1 = 0.f;
    float4 xpf[8];

    // ---- prologue ----
    for (int i = t; i < 1536; i += 256) {
        int q = i / 384, r = i % 384;
        int f = r / 48, r2 = r % 48;
        int h = r2 >> 2, ii = r2 & 3;
        int c = q * 4 + f * 16 + ii;              // c-interleaved to match staging quarters
        w2r_l[q * 388 + f * 48 + h * 4 + ii] = w2d[c * 12 + h];
    }
    if (t < 192) qs_l[t] = yraw[(size_t)n * 1152 + t];
    if (t < 144) qp_l[t] = qp_arr[(size_t)n * 144 + t];
    if (t < 12) {
        sq_l[t] = sq_arr[(size_t)n * 12 + t];
        pw_l[t] = 0.13608276348795434f * log1pf(__expf(tpw[t]));
        b2_l[t] = b2d[t];
        rmax_l[t] = -3.0e38f;
        rt_l[t] = (t < 9) ? rotm[n * 9 + t] : trans[n * 3 + (t - 9)];
    }
    if (t < 16) { rsum_l[t] = 0.f; alph_l[t] = 1.0f; }   // h 12-15 stay 1.0 forever
    const float maskn = mask[n];

    {   // initial x prefetch (tile 0), c-interleaved quarters
        const float* xr = x2d + ((size_t)n * NN_ + sm) * 128 + q4 * 4;
        #pragma unroll
        for (int f = 0; f < 8; ++f) xpf[f] = *(const float4*)&xr[f * 16];
    }
    __syncthreads();

    for (int mt = 0; mt < 16; ++mt) {
        const int m0 = mt * 64;
        // ===== STAGE: transpose-pack xpf -> bf16 x_lT[c][m]; at2 from fp32 registers =====
        #pragma unroll
        for (int f = 0; f < 8; ++f) {
            int c0 = q4 * 4 + f * 16;
            x_lT[c0 + 0][sm] = (unsigned short)((__float_as_uint(xpf[f].x) + 0x8000u) >> 16);
            x_lT[c0 + 1][sm] = (unsigned short)((__float_as_uint(xpf[f].y) + 0x8000u) >> 16);
            x_lT[c0 + 2][sm] = (unsigned short)((__float_as_uint(xpf[f].z) + 0x8000u) >> 16);
            x_lT[c0 + 3][sm] = (unsigned short)((__float_as_uint(xpf[f].w) + 0x8000u) >> 16);
        }
        {
            float at2[12];
            #pragma unroll
            for (int h = 0; h < 12; ++h) at2[h] = 0.f;
            #pragma unroll
            for (int f = 0; f < 8; ++f) {
                #pragma unroll
                for (int h = 0; h < 12; ++h) {
                    float4 wv4 = *(const float4*)&w2r_l[q4 * 388 + f * 48 + h * 4];
                    at2[h] += xpf[f].x * wv4.x + xpf[f].y * wv4.y + xpf[f].z * wv4.z + xpf[f].w * wv4.w;
                }
            }
            #pragma unroll
            for (int h = 0; h < 12; ++h) {
                at2[h] += __shfl_xor(at2[h], 1);
                at2[h] += __shfl_xor(at2[h], 2);
            }
            if (q4 == 0) {
                #pragma unroll
                for (int h = 0; h < 12; ++h) at2_l[sm][h] = at2[h];
            }
        }
        __syncthreads();   // (1) x_lT / at2_l ready

        // ===== LOGITS + wave-internal online softmax; prefetch next x =====
        {
            int m1 = (mt + 1 == 16) ? 0 : (m0 + 64);
            const float* xr = x2d + ((size_t)n * NN_ + m1 + sm) * 128 + q4 * 4;
            #pragma unroll
            for (int f = 0; f < 8; ++f) xpf[f] = *(const float4*)&xr[f * 16];
        }
        {
            const int mg = m0 + m3;
            const float* kb = kpackT4 + 4 * (size_t)mg;
            const float mko = 100000.0f * (1.0f - maskn * mask[mg]);
            #pragma unroll
            for (int e = 0; e < 3; ++e) {
                const int h = hg * 3 + e;
                float4 k0 = *(const float4*)&kb[(size_t)(h * 4 + 0) * 4096];
                float4 k1 = *(const float4*)&kb[(size_t)(h * 4 + 1) * 4096];
                float4 k2 = *(const float4*)&kb[(size_t)(h * 4 + 2) * 4096];
                float4 k3 = *(const float4*)&kb[(size_t)(h * 4 + 3) * 4096];
                float4 p0 = *(const float4*)&kb[(size_t)(48 + h) * 4096];
                float4 p1 = *(const float4*)&kb[(size_t)(60 + h) * 4096];
                float4 p2 = *(const float4*)&kb[(size_t)(72 + h) * 4096];
                float skm = skT[(size_t)h * 1024 + mg];
                const float4* qsn = (const float4*)&qs_l[h * 16];
                float dqs = qsn[0].x*k0.x + qsn[0].y*k0.y + qsn[0].z*k0.z + qsn[0].w*k0.w
                          + qsn[1].x*k1.x + qsn[1].y*k1.y + qsn[1].z*k1.z + qsn[1].w*k1.w
                          + qsn[2].x*k2.x + qsn[2].y*k2.y + qsn[2].z*k2.z + qsn[2].w*k2.w
                          + qsn[3].x*k3.x + qsn[3].y*k3.y + qsn[3].z*k3.z + qsn[3].w*k3.w;
                float4 qA = *(const float4*)&qp_l[h * 4];
                float4 qB = *(const float4*)&qp_l[48 + h * 4];
                float4 qC = *(const float4*)&qp_l[96 + h * 4];
                float qk = qA.x*p0.x + qA.y*p0.y + qA.z*p0.z + qA.w*p0.w
                         + qB.x*p1.x + qB.y*p1.y + qB.z*p1.z + qB.w*p1.w
                         + qC.x*p2.x + qC.y*p2.y + qC.z*p2.z + qC.w*p2.w;
                float pwh = pw_l[h];
                float lg = 0.14433756729740643f * dqs
                         + pwh * qk - 0.5f * pwh * (sq_l[h] + skm)
                         + 0.57735026918962576f * (at2_l[m3][h] + b2_l[h])
                         - mko;
                float tm = lg;
                tm = fmaxf(tm, __shfl_xor(tm, 1));
                tm = fmaxf(tm, __shfl_xor(tm, 2));
                tm = fmaxf(tm, __shfl_xor(tm, 4));
                tm = fmaxf(tm, __shfl_xor(tm, 8));
                tm = fmaxf(tm, __shfl_xor(tm, 16));
                tm = fmaxf(tm, __shfl_xor(tm, 32));
                float om = rmax_l[h];
                float nm = fmaxf(om, tm);
                float p = __expf(lg - nm);
                tlb[h][m3] = (unsigned short)((__float_as_uint(p) + 0x8000u) >> 16);
                float ps = p;
                ps += __shfl_xor(ps, 1);
                ps += __shfl_xor(ps, 2);
                ps += __shfl_xor(ps, 4);
                ps += __shfl_xor(ps, 8);
                ps += __shfl_xor(ps, 16);
                ps += __shfl_xor(ps, 32);
                if (m3 == 0) {
                    float al = __expf(om - nm);
                    rmax_l[h] = nm;
                    alph_l[h] = al;
                    rsum_l[h] = rsum_l[h] * al + ps;
                }
            }
        }
        __syncthreads();   // (2) tlb / alph ready

        // ===== ACCUM: res2d via MFMA + resF scalar =====
        {
            f32x4_t av = { alph_l[rowB], alph_l[rowB + 1], alph_l[rowB + 2], alph_l[rowB + 3] };
            accM[0] *= av;
            accM[1] *= av;
            bf16x8_t pA0 = *(const bf16x8_t*)&tlb[ln & 15][(ln >> 4) * 8];
            bf16x8_t pA1 = *(const bf16x8_t*)&tlb[ln & 15][32 + (ln >> 4) * 8];
            #pragma unroll
            for (int nt = 0; nt < 2; ++nt) {
                int c = wv * 32 + nt * 16 + (ln & 15);
                bf16x8_t xB0 = *(const bf16x8_t*)&x_lT[c][(ln >> 4) * 8];
                bf16x8_t xB1 = *(const bf16x8_t*)&x_lT[c][32 + (ln >> 4) * 8];
                accM[nt] = __builtin_amdgcn_mfma_f32_16x16x32_bf16(pA0, xB0, accM[nt], 0, 0, 0);
                accM[nt] = __builtin_amdgcn_mfma_f32_16x16x32_bf16(pA1, xB1, accM[nt], 0, 0, 0);
            }
        }
        if (t < 240) {
            float alf = alph_l[hF];
            accF0 *= alf; accF1 *= alf;
            const float* vb = vpack + (size_t)m0 * 480 + jF;
            #pragma unroll 4
            for (int mm = 0; mm < 64; mm += 4) {
                ushort4 pu = *(const ushort4*)&tlb[hF][mm];
                float pa0 = __uint_as_float((unsigned)pu.x << 16);
                float pa1 = __uint_as_float((unsigned)pu.y << 16);
                float pa2 = __uint_as_float((unsigned)pu.z << 16);
                float pa3 = __uint_as_float((unsigned)pu.w << 16);
                float2 v0 = *(const float2*)&vb[(size_t)(mm + 0) * 480];
                float2 v1 = *(const float2*)&vb[(size_t)(mm + 1) * 480];
                float2 v2 = *(const float2*)&vb[(size_t)(mm + 2) * 480];
                float2 v3 = *(const float2*)&vb[(size_t)(mm + 3) * 480];
                accF0 += pa0 * v0.x + pa1 * v1.x + pa2 * v2.x + pa3 * v3.x;
                accF1 += pa0 * v0.y + pa1 * v1.y + pa2 * v2.y + pa3 * v3.y;
            }
        }
        __syncthreads();   // (3) protect x_lT / tlb for next tile
    }

    // ================= epilogue =================
    #pragma unroll
    for (int nt = 0; nt < 2; ++nt) {
        #pragma unroll
        for (int r = 0; r < 4; ++r) {
            int row = rowB + r;
            if (row < 12) {
                int c = wv * 32 + nt * 16 + (ln & 15);
                fin[(size_t)n * DOUT_ + 576 + (size_t)row * 128 + c] = accM[nt][r] / rsum_l[row];
            }
        }
    }
    if (t < 240) {
        float inv = 1.f / rsum_l[hF];
        float vA = accF0 * inv, vB = accF1 * inv;
        if (jF < 192) {
            fin[(size_t)n * DOUT_ + jF]     = vA;
            fin[(size_t)n * DOUT_ + jF + 1] = vB;
        } else {
            pg_l[jF - 192] = vA;
            pg_l[jF - 191] = vB;
        }
    }
    __syncthreads();
    if (t < 96) {
        const int k = t;
        float c0 = pg_l[k]       - rt_l[9];
        float c1 = pg_l[96 + k]  - rt_l[10];
        float c2 = pg_l[192 + k] - rt_l[11];
        float r0 = rt_l[0] * c0 + rt_l[3] * c1 + rt_l[6] * c2;
        float r1 = rt_l[1] * c0 + rt_l[4] * c1 + rt_l[7] * c2;
        float r2 = rt_l[2] * c0 + rt_l[5] * c1 + rt_l[8] * c2;
        size_t base = (size_t)n * DOUT_;
        fin[base + 192 + k] = r0;
        fin[base + 288 + k] = r1;
        fin[base + 384 + k] = r2;
        fin[base + 480 + k] = sqrtf(1e-8f + r0 * r0 + r1 * r1 + r2 * r2);
    }
}

// ---------------- K5: out partials, split-K over 4 chunks of 528 ----------------
__global__ __launch_bounds__(256) void k_out(
    const float* __restrict__ fin, const float* __restrict__ wo,
    float* __restrict__ pout)
{
    __shared__ float a_l[64 * 52];
    __shared__ float b_l[48 * 68];
    const int t = threadIdx.x;
    const int m0 = blockIdx.x * 64, n0 = blockIdx.y * 64, kc = blockIdx.z;
    const int tx = t & 15, ty = t >> 4;
    float acc[4][4] = {};
    for (int k0 = kc * 528; k0 < kc * 528 + 528; k0 += 48) {
        #pragma unroll
        for (int e = 0; e < 3; ++e) {
            int idx = t + 256 * e;
            int r = idx / 12, c4 = (idx % 12) * 4;
            *(float4*)&a_l[r * 52 + c4] = *(const float4*)&fin[(size_t)(m0 + r) * DOUT_ + k0 + c4];
        }
        #pragma unroll
        for (int e = 0; e < 3; ++e) {
            int idx = t + 256 * e;
            int r = idx >> 4, c4 = (idx & 15) * 4;
            *(float4*)&b_l[r * 68 + c4] = *(const float4*)&wo[(size_t)(k0 + r) * 384 + n0 + c4];
        }
        __syncthreads();
        #pragma unroll 4
        for (int k = 0; k < 48; ++k) {
            float4 bv = *(const float4*)&b_l[k * 68 + tx * 4];
            #pragma unroll
            for (int i = 0; i < 4; ++i) {
                float av = a_l[(ty * 4 + i) * 52 + k];
                acc[i][0] += av * bv.x; acc[i][1] += av * bv.y;
                acc[i][2] += av * bv.z; acc[i][3] += av * bv.w;
            }
        }
        __syncthreads();
    }
    float* pr = pout + (size_t)kc * 393216;
    #pragma unroll
    for (int i = 0; i < 4; ++i) {
        float4 o;
        o.x = acc[i][0]; o.y = acc[i][1]; o.z = acc[i][2]; o.w = acc[i][3];
        *(float4*)&pr[(size_t)(m0 + ty * 4 + i) * 384 + n0 + tx * 4] = o;
    }
}

// ---------------- K6: sum split-K partials + bias ----------------
__global__ __launch_bounds__(256) void k_fin(
    const float* __restrict__ pout, const float* __restrict__ bo, float* __restrict__ out)
{
    int idx = blockIdx.x * 256 + threadIdx.x;
    float4 a = *(const float4*)&pout[(size_t)idx * 4];
    float4 b = *(const float4*)&pout[393216 + (size_t)idx * 4];
    float4 c = *(const float4*)&pout[786432 + (size_t)idx * 4];
    float4 d = *(const float4*)&pout[1179648 + (size_t)idx * 4];
    float4 bias = *(const float4*)&bo[(idx % 96) * 4];
    float4 o;
    o.x = a.x + b.x + c.x + d.x + bias.x;
    o.y = a.y + b.y + c.y + d.y + bias.y;
    o.z = a.z + b.z + c.z + d.z + bias.z;
    o.w = a.w + b.w + c.w + d.w + bias.w;
    *(float4*)&out[(size_t)idx * 4] = o;
}

extern "C" void kernel_launch(void* const* d_in, const int* in_sizes, int n_in,
                              void* d_out, int out_size, void* d_ws, size_t ws_size,
                              hipStream_t stream) {
    const float* in1   = (const float*)d_in[0];
    const float* x2d   = (const float*)d_in[1];
    const float* mask  = (const float*)d_in[2];
    const float* rotm  = (const float*)d_in[3];
    const float* trans = (const float*)d_in[4];
    const float* wq    = (const float*)d_in[5];
    const float* bq    = (const float*)d_in[6];
    const float* wkv   = (const float*)d_in[7];
    const float* bkv   = (const float*)d_in[8];
    const float* wqp   = (const float*)d_in[9];
    const float* bqp   = (const float*)d_in[10];
    const float* wkvp  = (const float*)d_in[11];
    const float* bkvp  = (const float*)d_in[12];
    const float* w2d   = (const float*)d_in[13];
    const float* b2d   = (const float*)d_in[14];
    const float* tpw   = (const float*)d_in[15];
    const float* wo    = (const float*)d_in[16];
    const float* bo    = (const float*)d_in[17];
    float* out = (float*)d_out;

    float* ws = (float*)d_ws;
    float* yraw    = ws;                    // 1,179,648
    float* qp_arr  = yraw + 1179648;        //   147,456
    float* kpackT4 = qp_arr + 147456;       //   360,448
    float* vpack   = kpackT4 + 360448;      //   491,520
    float* sq_arr  = vpack + 491520;        //    12,288
    float* fin     = sq_arr + 12288;        // 2,162,688
    float* pout    = fin + 2162688;         // 1,572,864
    float* skT     = pout + 1572864;        //    12,288

    hipLaunchKernelGGL(k_gemm1, dim3(16, 18), dim3(256), 0, stream,
        in1, wq, bq, wkv, bkv, wqp, bqp, wkvp, bkvp, yraw);
    hipLaunchKernelGGL(k_rot, dim3(256), dim3(256), 0, stream,
        yraw, rotm, trans, qp_arr, kpackT4, vpack, sq_arr, skT);
    hipLaunchKernelGGL(k_attn7, dim3(1024), dim3(256), 0, stream,
        x2d, mask, w2d, b2d, tpw, yraw, qp_arr, kpackT4, vpack, sq_arr, skT, rotm, trans, fin);
    hipLaunchKernelGGL(k_out, dim3(16, 6, 4), dim3(256), 0, stream, fin, wo, pout);
    hipLaunchKernelGGL(k_fin, dim3(384), dim3(256), 0, stream, pout, bo, out);
}

// Round 10
// 382.535 us; speedup vs baseline: 7.4341x; 1.0508x over previous
//
#include <hip/hip_runtime.h>
#include <math.h>

#define NN_ 1024
#define DOUT_ 2112
#define NOUT_ 384

using bf16x8_t = __attribute__((ext_vector_type(8))) short;
using f32x4_t  = __attribute__((ext_vector_type(4))) float;

// ---------------- K1: yraw[1024][1152] = in1 @ [wq|wkv|wqp|wkvp] + bias ----------------
__global__ __launch_bounds__(256) void k_gemm1(
    const float* __restrict__ in1,
    const float* __restrict__ wq, const float* __restrict__ bq,
    const float* __restrict__ wkv, const float* __restrict__ bkv,
    const float* __restrict__ wqp, const float* __restrict__ bqp,
    const float* __restrict__ wkvp, const float* __restrict__ bkvp,
    float* __restrict__ yraw)
{
    __shared__ float a_l[64 * 36];
    __shared__ float b_l[32 * 68];
    const int t = threadIdx.x;
    const int m0 = blockIdx.x * 64, j0 = blockIdx.y * 64;
    const int tx = t & 15, ty = t >> 4;
    float acc[4][4] = {};
    for (int k0 = 0; k0 < 384; k0 += 32) {
        #pragma unroll
        for (int e = 0; e < 2; ++e) {
            int idx = t + 256 * e;
            int r = idx >> 3, c4 = (idx & 7) * 4;
            *(float4*)&a_l[r * 36 + c4] = *(const float4*)&in1[(size_t)(m0 + r) * 384 + k0 + c4];
        }
        #pragma unroll
        for (int e = 0; e < 2; ++e) {
            int idx = t + 256 * e;
            int r = idx >> 4, c4 = (idx & 15) * 4;
            int j = j0 + c4;
            const float* w; int ncol, jj;
            if (j < 192)      { w = wq;   ncol = 192; jj = j; }
            else if (j < 576) { w = wkv;  ncol = 384; jj = j - 192; }
            else if (j < 720) { w = wqp;  ncol = 144; jj = j - 576; }
            else              { w = wkvp; ncol = 432; jj = j - 720; }
            *(float4*)&b_l[r * 68 + c4] = *(const float4*)&w[(size_t)(k0 + r) * ncol + jj];
        }
        __syncthreads();
        #pragma unroll 8
        for (int k = 0; k < 32; ++k) {
            float4 bv = *(const float4*)&b_l[k * 68 + tx * 4];
            #pragma unroll
            for (int i = 0; i < 4; ++i) {
                float av = a_l[(ty * 4 + i) * 36 + k];
                acc[i][0] += av * bv.x; acc[i][1] += av * bv.y;
                acc[i][2] += av * bv.z; acc[i][3] += av * bv.w;
            }
        }
        __syncthreads();
    }
    int j = j0 + tx * 4;
    float4 bias;
    {
        const float* b; int jj;
        if (j < 192)      { b = bq;   jj = j; }
        else if (j < 576) { b = bkv;  jj = j - 192; }
        else if (j < 720) { b = bqp;  jj = j - 576; }
        else              { b = bkvp; jj = j - 720; }
        bias = *(const float4*)&b[jj];
    }
    #pragma unroll
    for (int i = 0; i < 4; ++i) {
        float4 o;
        o.x = acc[i][0] + bias.x; o.y = acc[i][1] + bias.y;
        o.z = acc[i][2] + bias.z; o.w = acc[i][3] + bias.w;
        *(float4*)&yraw[(size_t)(m0 + ty * 4 + i) * 1152 + j] = o;
    }
}

// ---------------- K2: rotations + packing (K transposed for coalesced logits loads) ----
__global__ __launch_bounds__(256) void k_rot(
    const float* __restrict__ yraw, const float* __restrict__ rotm, const float* __restrict__ trans,
    float* __restrict__ qp_arr, float* __restrict__ kpackT4, float* __restrict__ vpack,
    float* __restrict__ sq_arr, float* __restrict__ skT)
{
    __shared__ float rt_l[4][12];
    const int t = threadIdx.x;
    const int n0 = blockIdx.x * 4;
    if (t < 48) {
        int n_ = t / 12, i = t % 12;
        rt_l[n_][i] = (i < 9) ? rotm[(n0 + n_) * 9 + i] : trans[(n0 + n_) * 3 + (i - 9)];
    }
    __syncthreads();
    const int n_ = t >> 6, l = t & 63;
    const int n = n0 + n_;
    const float* y = yraw + (size_t)n * 1152;
    const float* R = rt_l[n_];
    #pragma unroll
    for (int jj = 0; jj < 9; ++jj) {
        int o = l + 64 * jj;
        if (o < 144) {
            int a = o / 48, kk = o % 48;
            float v = R[9 + a] + R[a*3+0] * y[576 + kk] + R[a*3+1] * y[576 + 48 + kk] + R[a*3+2] * y[576 + 96 + kk];
            qp_arr[(size_t)n * 144 + o] = v;
        } else if (o < 288) {
            int o2 = o - 144;
            int a = o2 / 48, r2 = o2 % 48;
            int kk = (r2 >> 2) * 12 + (r2 & 3);
            float v = R[9 + a] + R[a*3+0] * y[720 + kk] + R[a*3+1] * y[720 + 144 + kk] + R[a*3+2] * y[720 + 288 + kk];
            int j = 192 + o2;
            kpackT4[(size_t)(j >> 2) * 4096 + 4 * n + (j & 3)] = v;
        } else {
            int o3 = o - 288;
            int a = o3 / 96, r2 = o3 % 96;
            int kk = (r2 >> 3) * 12 + 4 + (r2 & 7);
            float v = R[9 + a] + R[a*3+0] * y[720 + kk] + R[a*3+1] * y[720 + 144 + kk] + R[a*3+2] * y[720 + 288 + kk];
            vpack[(size_t)n * 480 + 192 + o3] = v;
        }
    }
    #pragma unroll
    for (int jj = 0; jj < 3; ++jj) {
        int o = l + 64 * jj;
        int h = o >> 4, r2 = o & 15;
        kpackT4[(size_t)(o >> 2) * 4096 + 4 * n + (o & 3)] = y[192 + h * 32 + r2];
        vpack[(size_t)n * 480 + o] = y[192 + h * 32 + 16 + r2];
    }
    if (l < 24) {
        int which = l / 12, h = l % 12;
        int base = (which == 0) ? 576 : 720;
        int stride = (which == 0) ? 48 : 144;
        float s = 0.f;
        #pragma unroll
        for (int a = 0; a < 3; ++a) {
            #pragma unroll
            for (int p = 0; p < 4; ++p) {
                int kk = (which == 0) ? (h * 4 + p) : (h * 12 + p);
                float v = R[9 + a] + R[a*3+0] * y[base + kk] + R[a*3+1] * y[base + stride + kk] + R[a*3+2] * y[base + 2 * stride + kk];
                s += v * v;
            }
        }
        if (which == 0) sq_arr[(size_t)n * 12 + h] = s;
        else            skT[(size_t)h * 1024 + n] = s;
    }
}

// ---------------- K3: fused flash IPA, one n per block, MT=64, MFMA at2 + res2d ----------
// plain __launch_bounds__(256): any min-waves hint caps VGPR at 64 and spills GBs (r3-5).
// Prefetch mapping == A-frag layout: lane (mm=ln&15, o=ln>>4) holds X[m=w*16+mm][c=kk*32+o*8+j]
//   at2:   D[m][h] = X·W2   : A=xpf(bf16), B=w2bT[h][c] (c-contig), D row=m,col=h
//   res2d: D[h][c] = P·X    : A=tlb[h][m], B=x_lT[c][m] (m-contig), D row=h,col=c
__global__ __launch_bounds__(256) void k_attn8(
    const float* __restrict__ x2d, const float* __restrict__ mask,
    const float* __restrict__ w2d, const float* __restrict__ b2d, const float* __restrict__ tpw,
    const float* __restrict__ yraw, const float* __restrict__ qp_arr,
    const float* __restrict__ kpackT4, const float* __restrict__ vpack,
    const float* __restrict__ sq_arr, const float* __restrict__ skT,
    const float* __restrict__ rotm, const float* __restrict__ trans,
    float* __restrict__ fin)
{
    __shared__ unsigned short x_lT[128][72];  // 18.4 KB bf16 [c][m]
    __shared__ unsigned short tlb[16][72];    // 2.3 KB bf16 P [h][m]
    __shared__ unsigned short w2bT[16][132];  // 4.2 KB bf16 W2^T [h][c], rows 12-15 zero
    __shared__ float at2_l[64][13];
    __shared__ float qs_l[192], qp_l[144];
    __shared__ float sq_l[12], pw_l[12], b2_l[12];
    __shared__ float rmax_l[12], rsum_l[16], alph_l[16];
    __shared__ float rt_l[12];
    __shared__ float pg_l[288];

    const int t = threadIdx.x;
    const int n = blockIdx.x;

    const int wv = t >> 6, ln = t & 63;    // wave, lane
    const int mmS = ln & 15, oS = ln >> 4; // stage/A-frag: m-sub, c-octet
    const int m3 = t & 63, hg = t >> 6;    // logits: lane=m, wave=h-trio
    const int rowB = (ln >> 4) * 4;        // MFMA D rows this lane holds
    const int jF = 2 * t;                  // resF: j pair (t<240)
    const int hF = (jF < 192) ? (jF >> 4) : (((jF - 192) % 96) >> 3);

    f32x4_t accM[2] = {{0.f, 0.f, 0.f, 0.f}, {0.f, 0.f, 0.f, 0.f}};
    float accF0 = 0.f, accF1 = 0.f;
    float4 xpf[8];   // [2*kk], [2*kk+1]: 8 floats of c at kk*32+oS*8

    // ---- prologue ----
    for (int i = t; i < 2112; i += 256) {   // w2bT: [h][c], zero-padded
        int h = i / 132, c = i % 132;
        unsigned short v = 0;
        if (h < 12 && c < 128) v = (unsigned short)((__float_as_uint(w2d[c * 12 + h]) + 0x8000u) >> 16);
        w2bT[h][c] = v;
    }
    if (t < 192) qs_l[t] = yraw[(size_t)n * 1152 + t];
    if (t < 144) qp_l[t] = qp_arr[(size_t)n * 144 + t];
    if (t < 12) {
        sq_l[t] = sq_arr[(size_t)n * 12 + t];
        pw_l[t] = 0.13608276348795434f * log1pf(__expf(tpw[t]));
        b2_l[t] = b2d[t];
        rmax_l[t] = -3.0e38f;
        rt_l[t] = (t < 9) ? rotm[n * 9 + t] : trans[n * 3 + (t - 9)];
    }
    if (t < 16) { rsum_l[t] = 0.f; alph_l[t] = 1.0f; }
    const float maskn = mask[n];

    {   // initial x prefetch (tile 0), A-frag-aligned mapping
        const float* xr = x2d + ((size_t)n * NN_ + wv * 16 + mmS) * 128 + oS * 8;
        #pragma unroll
        for (int kk = 0; kk < 4; ++kk) {
            xpf[2 * kk]     = *(const float4*)&xr[kk * 32];
            xpf[2 * kk + 1] = *(const float4*)&xr[kk * 32 + 4];
        }
    }
    __syncthreads();

    for (int mt = 0; mt < 16; ++mt) {
        const int m0 = mt * 64;
        // ===== STAGE: pack xpf -> bf16 (A-frags + x_lT writes) + at2 via MFMA =====
        {
            bf16x8_t afr[4];
            #pragma unroll
            for (int kk = 0; kk < 4; ++kk) {
                unsigned short e0 = (unsigned short)((__float_as_uint(xpf[2*kk].x)   + 0x8000u) >> 16);
                unsigned short e1 = (unsigned short)((__float_as_uint(xpf[2*kk].y)   + 0x8000u) >> 16);
                unsigned short e2 = (unsigned short)((__float_as_uint(xpf[2*kk].z)   + 0x8000u) >> 16);
                unsigned short e3 = (unsigned short)((__float_as_uint(xpf[2*kk].w)   + 0x8000u) >> 16);
                unsigned short e4 = (unsigned short)((__float_as_uint(xpf[2*kk+1].x) + 0x8000u) >> 16);
                unsigned short e5 = (unsigned short)((__float_as_uint(xpf[2*kk+1].y) + 0x8000u) >> 16);
                unsigned short e6 = (unsigned short)((__float_as_uint(xpf[2*kk+1].z) + 0x8000u) >> 16);
                unsigned short e7 = (unsigned short)((__float_as_uint(xpf[2*kk+1].w) + 0x8000u) >> 16);
                afr[kk][0] = (short)e0; afr[kk][1] = (short)e1; afr[kk][2] = (short)e2; afr[kk][3] = (short)e3;
                afr[kk][4] = (short)e4; afr[kk][5] = (short)e5; afr[kk][6] = (short)e6; afr[kk][7] = (short)e7;
                const int c0 = kk * 32 + oS * 8;
                const int m = wv * 16 + mmS;
                x_lT[c0 + 0][m] = e0; x_lT[c0 + 1][m] = e1;
                x_lT[c0 + 2][m] = e2; x_lT[c0 + 3][m] = e3;
                x_lT[c0 + 4][m] = e4; x_lT[c0 + 5][m] = e5;
                x_lT[c0 + 6][m] = e6; x_lT[c0 + 7][m] = e7;
            }
            f32x4_t aA = {0.f, 0.f, 0.f, 0.f};
            #pragma unroll
            for (int kk = 0; kk < 4; ++kk) {
                bf16x8_t bfW = *(const bf16x8_t*)&w2bT[ln & 15][kk * 32 + (ln >> 4) * 8];
                aA = __builtin_amdgcn_mfma_f32_16x16x32_bf16(afr[kk], bfW, aA, 0, 0, 0);
            }
            const int hC = ln & 15;
            if (hC < 12) {
                #pragma unroll
                for (int r = 0; r < 4; ++r)
                    at2_l[wv * 16 + (ln >> 4) * 4 + r][hC] = aA[r];
            }
        }
        __syncthreads();   // (1) x_lT / at2_l ready

        // ===== LOGITS + wave-internal online softmax; prefetch next x =====
        {
            int m1 = (mt + 1 == 16) ? 0 : (m0 + 64);
            const float* xr = x2d + ((size_t)n * NN_ + m1 + wv * 16 + mmS) * 128 + oS * 8;
            #pragma unroll
            for (int kk = 0; kk < 4; ++kk) {
                xpf[2 * kk]     = *(const float4*)&xr[kk * 32];
                xpf[2 * kk + 1] = *(const float4*)&xr[kk * 32 + 4];
            }
        }
        {
            const int mg = m0 + m3;
            const float* kb = kpackT4 + 4 * (size_t)mg;
            const float mko = 100000.0f * (1.0f - maskn * mask[mg]);
            #pragma unroll
            for (int e = 0; e < 3; ++e) {
                const int h = hg * 3 + e;
                float4 k0 = *(const float4*)&kb[(size_t)(h * 4 + 0) * 4096];
                float4 k1 = *(const float4*)&kb[(size_t)(h * 4 + 1) * 4096];
                float4 k2 = *(const float4*)&kb[(size_t)(h * 4 + 2) * 4096];
                float4 k3 = *(const float4*)&kb[(size_t)(h * 4 + 3) * 4096];
                float4 p0 = *(const float4*)&kb[(size_t)(48 + h) * 4096];
                float4 p1 = *(const float4*)&kb[(size_t)(60 + h) * 4096];
                float4 p2 = *(const float4*)&kb[(size_t)(72 + h) * 4096];
                float skm = skT[(size_t)h * 1024 + mg];
                const float4* qsn = (const float4*)&qs_l[h * 16];
                float dqs = qsn[0].x*k0.x + qsn[0].y*k0.y + qsn[0].z*k0.z + qsn[0].w*k0.w
                          + qsn[1].x*k1.x + qsn[1].y*k1.y + qsn[1].z*k1.z + qsn[1].w*k1.w
                          + qsn[2].x*k2.x + qsn[2].y*k2.y + qsn[2].z*k2.z + qsn[2].w*k2.w
                          + qsn[3].x*k3.x + qsn[3].y*k3.y + qsn[3].z*k3.z + qsn[3].w*k3.w;
                float4 qA = *(const float4*)&qp_l[h * 4];
                float4 qB = *(const float4*)&qp_l[48 + h * 4];
                float4 qC = *(const float4*)&qp_l[96 + h * 4];
                float qk = qA.x*p0.x + qA.y*p0.y + qA.z*p0.z + qA.w*p0.w
                         + qB.x*p1.x + qB.y*p1.y + qB.z*p1.z + qB.w*p1.w
                         + qC.x*p2.x + qC.y*p2.y + qC.z*p2.z + qC.w*p2.w;
                float pwh = pw_l[h];
                float lg = 0.14433756729740643f * dqs
                         + pwh * qk - 0.5f * pwh * (sq_l[h] + skm)
                         + 0.57735026918962576f * (at2_l[m3][h] + b2_l[h])
                         - mko;
                float tm = lg;
                tm = fmaxf(tm, __shfl_xor(tm, 1));
                tm = fmaxf(tm, __shfl_xor(tm, 2));
                tm = fmaxf(tm, __shfl_xor(tm, 4));
                tm = fmaxf(tm, __shfl_xor(tm, 8));
                tm = fmaxf(tm, __shfl_xor(tm, 16));
                tm = fmaxf(tm, __shfl_xor(tm, 32));
                float om = rmax_l[h];
                float nm = fmaxf(om, tm);
                float p = __expf(lg - nm);
                tlb[h][m3] = (unsigned short)((__float_as_uint(p) + 0x8000u) >> 16);
                float ps = p;
                ps += __shfl_xor(ps, 1);
                ps += __shfl_xor(ps, 2);
                ps += __shfl_xor(ps, 4);
                ps += __shfl_xor(ps, 8);
                ps += __shfl_xor(ps, 16);
                ps += __shfl_xor(ps, 32);
                if (m3 == 0) {
                    float al = __expf(om - nm);
                    rmax_l[h] = nm;
                    alph_l[h] = al;
                    rsum_l[h] = rsum_l[h] * al + ps;
                }
            }
        }
        __syncthreads();   // (2) tlb / alph ready

        // ===== ACCUM: res2d via MFMA + resF scalar =====
        {
            f32x4_t av = { alph_l[rowB], alph_l[rowB + 1], alph_l[rowB + 2], alph_l[rowB + 3] };
            accM[0] *= av;
            accM[1] *= av;
            bf16x8_t pA0 = *(const bf16x8_t*)&tlb[ln & 15][(ln >> 4) * 8];
            bf16x8_t pA1 = *(const bf16x8_t*)&tlb[ln & 15][32 + (ln >> 4) * 8];
            #pragma unroll
            for (int nt = 0; nt < 2; ++nt) {
                int c = wv * 32 + nt * 16 + (ln & 15);
                bf16x8_t xB0 = *(const bf16x8_t*)&x_lT[c][(ln >> 4) * 8];
                bf16x8_t xB1 = *(const bf16x8_t*)&x_lT[c][32 + (ln >> 4) * 8];
                accM[nt] = __builtin_amdgcn_mfma_f32_16x16x32_bf16(pA0, xB0, accM[nt], 0, 0, 0);
                accM[nt] = __builtin_amdgcn_mfma_f32_16x16x32_bf16(pA1, xB1, accM[nt], 0, 0, 0);
            }
        }
        if (t < 240) {
            float alf = alph_l[hF];
            accF0 *= alf; accF1 *= alf;
            const float* vb = vpack + (size_t)m0 * 480 + jF;
            #pragma unroll 4
            for (int mm = 0; mm < 64; mm += 4) {
                ushort4 pu = *(const ushort4*)&tlb[hF][mm];
                float pa0 = __uint_as_float((unsigned)pu.x << 16);
                float pa1 = __uint_as_float((unsigned)pu.y << 16);
                float pa2 = __uint_as_float((unsigned)pu.z << 16);
                float pa3 = __uint_as_float((unsigned)pu.w << 16);
                float2 v0 = *(const float2*)&vb[(size_t)(mm + 0) * 480];
                float2 v1 = *(const float2*)&vb[(size_t)(mm + 1) * 480];
                float2 v2 = *(const float2*)&vb[(size_t)(mm + 2) * 480];
                float2 v3 = *(const float2*)&vb[(size_t)(mm + 3) * 480];
                accF0 += pa0 * v0.x + pa1 * v1.x + pa2 * v2.x + pa3 * v3.x;
                accF1 += pa0 * v0.y + pa1 * v1.y + pa2 * v2.y + pa3 * v3.y;
            }
        }
        __syncthreads();   // (3) protect x_lT / tlb / at2_l for next tile
    }

    // ================= epilogue =================
    #pragma unroll
    for (int nt = 0; nt < 2; ++nt) {
        #pragma unroll
        for (int r = 0; r < 4; ++r) {
            int row = rowB + r;
            if (row < 12) {
                int c = wv * 32 + nt * 16 + (ln & 15);
                fin[(size_t)n * DOUT_ + 576 + (size_t)row * 128 + c] = accM[nt][r] / rsum_l[row];
            }
        }
    }
    if (t < 240) {
        float inv = 1.f / rsum_l[hF];
        float vA = accF0 * inv, vB = accF1 * inv;
        if (jF < 192) {
            fin[(size_t)n * DOUT_ + jF]     = vA;
            fin[(size_t)n * DOUT_ + jF + 1] = vB;
        } else {
            pg_l[jF - 192] = vA;
            pg_l[jF - 191] = vB;
        }
    }
    __syncthreads();
    if (t < 96) {
        const int k = t;
        float c0 = pg_l[k]       - rt_l[9];
        float c1 = pg_l[96 + k]  - rt_l[10];
        float c2 = pg_l[192 + k] - rt_l[11];
        float r0 = rt_l[0] * c0 + rt_l[3] * c1 + rt_l[6] * c2;
        float r1 = rt_l[1] * c0 + rt_l[4] * c1 + rt_l[7] * c2;
        float r2 = rt_l[2] * c0 + rt_l[5] * c1 + rt_l[8] * c2;
        size_t base = (size_t)n * DOUT_;
        fin[base + 192 + k] = r0;
        fin[base + 288 + k] = r1;
        fin[base + 384 + k] = r2;
        fin[base + 480 + k] = sqrtf(1e-8f + r0 * r0 + r1 * r1 + r2 * r2);
    }
}

// ---------------- K5: out partials, split-K over 4 chunks of 528 ----------------
__global__ __launch_bounds__(256) void k_out(
    const float* __restrict__ fin, const float* __restrict__ wo,
    float* __restrict__ pout)
{
    __shared__ float a_l[64 * 52];
    __shared__ float b_l[48 * 68];
    const int t = threadIdx.x;
    const int m0 = blockIdx.x * 64, n0 = blockIdx.y * 64, kc = blockIdx.z;
    const int tx = t & 15, ty = t >> 4;
    float acc[4][4] = {};
    for (int k0 = kc * 528; k0 < kc * 528 + 528; k0 += 48) {
        #pragma unroll
        for (int e = 0; e < 3; ++e) {
            int idx = t + 256 * e;
            int r = idx / 12, c4 = (idx % 12) * 4;
            *(float4*)&a_l[r * 52 + c4] = *(const float4*)&fin[(size_t)(m0 + r) * DOUT_ + k0 + c4];
        }
        #pragma unroll
        for (int e = 0; e < 3; ++e) {
            int idx = t + 256 * e;
            int r = idx >> 4, c4 = (idx & 15) * 4;
            *(float4*)&b_l[r * 68 + c4] = *(const float4*)&wo[(size_t)(k0 + r) * 384 + n0 + c4];
        }
        __syncthreads();
        #pragma unroll 4
        for (int k = 0; k < 48; ++k) {
            float4 bv = *(const float4*)&b_l[k * 68 + tx * 4];
            #pragma unroll
            for (int i = 0; i < 4; ++i) {
                float av = a_l[(ty * 4 + i) * 52 + k];
                acc[i][0] += av * bv.x; acc[i][1] += av * bv.y;
                acc[i][2] += av * bv.z; acc[i][3] += av * bv.w;
            }
        }
        __syncthreads();
    }
    float* pr = pout + (size_t)kc * 393216;
    #pragma unroll
    for (int i = 0; i < 4; ++i) {
        float4 o;
        o.x = acc[i][0]; o.y = acc[i][1]; o.z = acc[i][2]; o.w = acc[i][3];
        *(float4*)&pr[(size_t)(m0 + ty * 4 + i) * 384 + n0 + tx * 4] = o;
    }
}

// ---------------- K6: sum split-K partials + bias ----------------
__global__ __launch_bounds__(256) void k_fin(
    const float* __restrict__ pout, const float* __restrict__ bo, float* __restrict__ out)
{
    int idx = blockIdx.x * 256 + threadIdx.x;
    float4 a = *(const float4*)&pout[(size_t)idx * 4];
    float4 b = *(const float4*)&pout[393216 + (size_t)idx * 4];
    float4 c = *(const float4*)&pout[786432 + (size_t)idx * 4];
    float4 d = *(const float4*)&pout[1179648 + (size_t)idx * 4];
    float4 bias = *(const float4*)&bo[(idx % 96) * 4];
    float4 o;
    o.x = a.x + b.x + c.x + d.x + bias.x;
    o.y = a.y + b.y + c.y + d.y + bias.y;
    o.z = a.z + b.z + c.z + d.z + bias.z;
    o.w = a.w + b.w + c.w + d.w + bias.w;
    *(float4*)&out[(size_t)idx * 4] = o;
}

extern "C" void kernel_launch(void* const* d_in, const int* in_sizes, int n_in,
                              void* d_out, int out_size, void* d_ws, size_t ws_size,
                              hipStream_t stream) {
    const float* in1   = (const float*)d_in[0];
    const float* x2d   = (const float*)d_in[1];
    const float* mask  = (const float*)d_in[2];
    const float* rotm  = (const float*)d_in[3];
    const float* trans = (const float*)d_in[4];
    const float* wq    = (const float*)d_in[5];
    const float* bq    = (const float*)d_in[6];
    const float* wkv   = (const float*)d_in[7];
    const float* bkv   = (const float*)d_in[8];
    const float* wqp   = (const float*)d_in[9];
    const float* bqp   = (const float*)d_in[10];
    const float* wkvp  = (const float*)d_in[11];
    const float* bkvp  = (const float*)d_in[12];
    const float* w2d   = (const float*)d_in[13];
    const float* b2d   = (const float*)d_in[14];
    const float* tpw   = (const float*)d_in[15];
    const float* wo    = (const float*)d_in[16];
    const float* bo    = (const float*)d_in[17];
    float* out = (float*)d_out;

    float* ws = (float*)d_ws;
    float* yraw    = ws;                    // 1,179,648
    float* qp_arr  = yraw + 1179648;        //   147,456
    float* kpackT4 = qp_arr + 147456;       //   360,448
    float* vpack   = kpackT4 + 360448;      //   491,520
    float* sq_arr  = vpack + 491520;        //    12,288
    float* fin     = sq_arr + 12288;        // 2,162,688
    float* pout    = fin + 2162688;         // 1,572,864
    float* skT     = pout + 1572864;        //    12,288

    hipLaunchKernelGGL(k_gemm1, dim3(16, 18), dim3(256), 0, stream,
        in1, wq, bq, wkv, bkv, wqp, bqp, wkvp, bkvp, yraw);
    hipLaunchKernelGGL(k_rot, dim3(256), dim3(256), 0, stream,
        yraw, rotm, trans, qp_arr, kpackT4, vpack, sq_arr, skT);
    hipLaunchKernelGGL(k_attn8, dim3(1024), dim3(256), 0, stream,
        x2d, mask, w2d, b2d, tpw, yraw, qp_arr, kpackT4, vpack, sq_arr, skT, rotm, trans, fin);
    hipLaunchKernelGGL(k_out, dim3(16, 6, 4), dim3(256), 0, stream, fin, wo, pout);
    hipLaunchKernelGGL(k_fin, dim3(384), dim3(256), 0, stream, pout, bo, out);
}

// Round 11
// 360.543 us; speedup vs baseline: 7.8875x; 1.0610x over previous
//
#include <hip/hip_runtime.h>
#include <math.h>

#define NN_ 1024
#define DOUT_ 2112
#define NOUT_ 384

using f16x8_t = __attribute__((ext_vector_type(8))) _Float16;
using f32x4_t = __attribute__((ext_vector_type(4))) float;

// ---------------- K1: yraw[1024][1152] = in1 @ [wq|wkv|wqp|wkvp] + bias ----------------
__global__ __launch_bounds__(256) void k_gemm1(
    const float* __restrict__ in1,
    const float* __restrict__ wq, const float* __restrict__ bq,
    const float* __restrict__ wkv, const float* __restrict__ bkv,
    const float* __restrict__ wqp, const float* __restrict__ bqp,
    const float* __restrict__ wkvp, const float* __restrict__ bkvp,
    float* __restrict__ yraw)
{
    __shared__ float a_l[64 * 36];
    __shared__ float b_l[32 * 68];
    const int t = threadIdx.x;
    const int m0 = blockIdx.x * 64, j0 = blockIdx.y * 64;
    const int tx = t & 15, ty = t >> 4;
    float acc[4][4] = {};
    for (int k0 = 0; k0 < 384; k0 += 32) {
        #pragma unroll
        for (int e = 0; e < 2; ++e) {
            int idx = t + 256 * e;
            int r = idx >> 3, c4 = (idx & 7) * 4;
            *(float4*)&a_l[r * 36 + c4] = *(const float4*)&in1[(size_t)(m0 + r) * 384 + k0 + c4];
        }
        #pragma unroll
        for (int e = 0; e < 2; ++e) {
            int idx = t + 256 * e;
            int r = idx >> 4, c4 = (idx & 15) * 4;
            int j = j0 + c4;
            const float* w; int ncol, jj;
            if (j < 192)      { w = wq;   ncol = 192; jj = j; }
            else if (j < 576) { w = wkv;  ncol = 384; jj = j - 192; }
            else if (j < 720) { w = wqp;  ncol = 144; jj = j - 576; }
            else              { w = wkvp; ncol = 432; jj = j - 720; }
            *(float4*)&b_l[r * 68 + c4] = *(const float4*)&w[(size_t)(k0 + r) * ncol + jj];
        }
        __syncthreads();
        #pragma unroll 8
        for (int k = 0; k < 32; ++k) {
            float4 bv = *(const float4*)&b_l[k * 68 + tx * 4];
            #pragma unroll
            for (int i = 0; i < 4; ++i) {
                float av = a_l[(ty * 4 + i) * 36 + k];
                acc[i][0] += av * bv.x; acc[i][1] += av * bv.y;
                acc[i][2] += av * bv.z; acc[i][3] += av * bv.w;
            }
        }
        __syncthreads();
    }
    int j = j0 + tx * 4;
    float4 bias;
    {
        const float* b; int jj;
        if (j < 192)      { b = bq;   jj = j; }
        else if (j < 576) { b = bkv;  jj = j - 192; }
        else if (j < 720) { b = bqp;  jj = j - 576; }
        else              { b = bkvp; jj = j - 720; }
        bias = *(const float4*)&b[jj];
    }
    #pragma unroll
    for (int i = 0; i < 4; ++i) {
        float4 o;
        o.x = acc[i][0] + bias.x; o.y = acc[i][1] + bias.y;
        o.z = acc[i][2] + bias.z; o.w = acc[i][3] + bias.w;
        *(float4*)&yraw[(size_t)(m0 + ty * 4 + i) * 1152 + j] = o;
    }
}

// ---------------- K2: rotations + packing ----------------
// kpackT4: (j,m) at (j>>2)*4096 + 4m + (j&3); skT[h*1024+m]
// vT (fp16): [j][m], j in [0,512): j<192 vs(h*16+s); 192..479 vp(a*96+h*8+p); 480+ zero
__global__ __launch_bounds__(256) void k_rot(
    const float* __restrict__ yraw, const float* __restrict__ rotm, const float* __restrict__ trans,
    float* __restrict__ qp_arr, float* __restrict__ kpackT4, _Float16* __restrict__ vT,
    float* __restrict__ sq_arr, float* __restrict__ skT)
{
    __shared__ float rt_l[4][12];
    const int t = threadIdx.x;
    const int n0 = blockIdx.x * 4;
    if (t < 48) {
        int n_ = t / 12, i = t % 12;
        rt_l[n_][i] = (i < 9) ? rotm[(n0 + n_) * 9 + i] : trans[(n0 + n_) * 3 + (i - 9)];
    }
    __syncthreads();
    const int n_ = t >> 6, l = t & 63;
    const int n = n0 + n_;
    const float* y = yraw + (size_t)n * 1152;
    const float* R = rt_l[n_];
    #pragma unroll
    for (int jj = 0; jj < 9; ++jj) {
        int o = l + 64 * jj;
        if (o < 144) {
            int a = o / 48, kk = o % 48;
            float v = R[9 + a] + R[a*3+0] * y[576 + kk] + R[a*3+1] * y[576 + 48 + kk] + R[a*3+2] * y[576 + 96 + kk];
            qp_arr[(size_t)n * 144 + o] = v;
        } else if (o < 288) {
            int o2 = o - 144;
            int a = o2 / 48, r2 = o2 % 48;
            int kk = (r2 >> 2) * 12 + (r2 & 3);
            float v = R[9 + a] + R[a*3+0] * y[720 + kk] + R[a*3+1] * y[720 + 144 + kk] + R[a*3+2] * y[720 + 288 + kk];
            int j = 192 + o2;
            kpackT4[(size_t)(j >> 2) * 4096 + 4 * n + (j & 3)] = v;
        } else {
            int o3 = o - 288;
            int a = o3 / 96, r2 = o3 % 96;
            int kk = (r2 >> 3) * 12 + 4 + (r2 & 7);
            float v = R[9 + a] + R[a*3+0] * y[720 + kk] + R[a*3+1] * y[720 + 144 + kk] + R[a*3+2] * y[720 + 288 + kk];
            vT[(size_t)(192 + o3) * 1024 + n] = (_Float16)v;
        }
    }
    #pragma unroll
    for (int jj = 0; jj < 3; ++jj) {
        int o = l + 64 * jj;
        int h = o >> 4, r2 = o & 15;
        kpackT4[(size_t)(o >> 2) * 4096 + 4 * n + (o & 3)] = y[192 + h * 32 + r2];
        vT[(size_t)o * 1024 + n] = (_Float16)y[192 + h * 32 + 16 + r2];
    }
    if (l < 32) vT[(size_t)(480 + l) * 1024 + n] = (_Float16)0.f;
    if (l < 24) {
        int which = l / 12, h = l % 12;
        int base = (which == 0) ? 576 : 720;
        int stride = (which == 0) ? 48 : 144;
        float s = 0.f;
        #pragma unroll
        for (int a = 0; a < 3; ++a) {
            #pragma unroll
            for (int p = 0; p < 4; ++p) {
                int kk = (which == 0) ? (h * 4 + p) : (h * 12 + p);
                float v = R[9 + a] + R[a*3+0] * y[base + kk] + R[a*3+1] * y[base + stride + kk] + R[a*3+2] * y[base + 2 * stride + kk];
                s += v * v;
            }
        }
        if (which == 0) sq_arr[(size_t)n * 12 + h] = s;
        else            skT[(size_t)h * 1024 + n] = s;
    }
}

// ---------------- K3: fused flash IPA, one n/block, MT=64, MFMA at2+res2d+resF (fp16) ----
// plain __launch_bounds__(256): any min-waves hint caps VGPR at 64 and spills GBs (r3-5).
// A-frag: lane holds A[row=ln&15][k=(ln>>4)*8+j]; D: col=ln&15, row=(ln>>4)*4+reg.
__global__ __launch_bounds__(256) void k_attn9(
    const float* __restrict__ x2d, const float* __restrict__ mask,
    const float* __restrict__ w2d, const float* __restrict__ b2d, const float* __restrict__ tpw,
    const float* __restrict__ yraw, const float* __restrict__ qp_arr,
    const float* __restrict__ kpackT4, const _Float16* __restrict__ vT,
    const float* __restrict__ sq_arr, const float* __restrict__ skT,
    const float* __restrict__ rotm, const float* __restrict__ trans,
    float* __restrict__ fin)
{
    __shared__ _Float16 x_lT[128][72];   // 18.4 KB [c][m]
    __shared__ _Float16 tlb[16][72];     // 2.3 KB P [h][m]; rows 12-15 zeroed
    __shared__ _Float16 w2bT[16][136];   // 4.4 KB W2^T [h][c], zero-padded
    __shared__ float at2_l[64][13];
    __shared__ float qs_l[192], qp_l[144];
    __shared__ float sq_l[12], pw_l[12], b2_l[12];
    __shared__ float rmax_l[12], rsum_l[16], alph_l[16];
    __shared__ float rt_l[12];
    __shared__ float pg_l[288];

    const int t = threadIdx.x;
    const int n = blockIdx.x;

    const int wv = t >> 6, ln = t & 63;    // wave, lane
    const int mmS = ln & 15, oS = ln >> 4; // A-frag: m-sub, c/k-octet
    const int m3 = t & 63, hg = t >> 6;    // logits: lane=m, wave=h-trio
    const int rowB = (ln >> 4) * 4;        // D rows this lane holds

    f32x4_t accM[2] = {{0.f,0.f,0.f,0.f},{0.f,0.f,0.f,0.f}};
    f32x4_t accF[8];
    #pragma unroll
    for (int jt = 0; jt < 8; ++jt) accF[jt] = (f32x4_t){0.f,0.f,0.f,0.f};
    f16x8_t afr[4];   // next-tile X A-frags (fp16, packed at prefetch)

    // ---- prologue ----
    for (int i = t; i < 2176; i += 256) {   // w2bT zero-padded
        int h = i / 136, c = i % 136;
        w2bT[h][c] = (h < 12 && c < 128) ? (_Float16)w2d[c * 12 + h] : (_Float16)0.f;
    }
    tlb[12 + (t >> 6)][t & 63] = (_Float16)0.f;   // zero garbage rows 12-15 (cols 0-63 used)
    if (t < 192) qs_l[t] = yraw[(size_t)n * 1152 + t];
    if (t < 144) qp_l[t] = qp_arr[(size_t)n * 144 + t];
    if (t < 12) {
        sq_l[t] = sq_arr[(size_t)n * 12 + t];
        pw_l[t] = 0.13608276348795434f * log1pf(__expf(tpw[t]));
        b2_l[t] = b2d[t];
        rmax_l[t] = -3.0e38f;
        rt_l[t] = (t < 9) ? rotm[n * 9 + t] : trans[n * 3 + (t - 9)];
    }
    if (t < 16) { rsum_l[t] = 0.f; alph_l[t] = 1.0f; }
    const float maskn = mask[n];

    {   // initial prefetch (tile 0): load fp32, pack to fp16 A-frags
        const float* xr = x2d + ((size_t)n * NN_ + wv * 16 + mmS) * 128 + oS * 8;
        #pragma unroll
        for (int kk = 0; kk < 4; ++kk) {
            float4 a = *(const float4*)&xr[kk * 32];
            float4 b = *(const float4*)&xr[kk * 32 + 4];
            f16x8_t f;
            f[0]=(_Float16)a.x; f[1]=(_Float16)a.y; f[2]=(_Float16)a.z; f[3]=(_Float16)a.w;
            f[4]=(_Float16)b.x; f[5]=(_Float16)b.y; f[6]=(_Float16)b.z; f[7]=(_Float16)b.w;
            afr[kk] = f;
        }
    }
    __syncthreads();

    for (int mt = 0; mt < 16; ++mt) {
        const int m0 = mt * 64;
        // ===== STAGE: afr -> x_lT + at2 via MFMA =====
        {
            const int m = wv * 16 + mmS;
            #pragma unroll
            for (int kk = 0; kk < 4; ++kk) {
                const int c0 = kk * 32 + oS * 8;
                #pragma unroll
                for (int i = 0; i < 8; ++i) x_lT[c0 + i][m] = afr[kk][i];
            }
            f32x4_t aA = {0.f, 0.f, 0.f, 0.f};
            #pragma unroll
            for (int kk = 0; kk < 4; ++kk) {
                f16x8_t bfW = *(const f16x8_t*)&w2bT[ln & 15][kk * 32 + (ln >> 4) * 8];
                aA = __builtin_amdgcn_mfma_f32_16x16x32_f16(afr[kk], bfW, aA, 0, 0, 0);
            }
            const int hC = ln & 15;
            if (hC < 12) {
                #pragma unroll
                for (int r = 0; r < 4; ++r)
                    at2_l[wv * 16 + (ln >> 4) * 4 + r][hC] = aA[r];
            }
        }
        __syncthreads();   // (1) x_lT / at2_l ready

        // ===== LOGITS + wave-internal online softmax; prefetch+pack next x =====
        {
            int m1 = (mt + 1 == 16) ? 0 : (m0 + 64);
            const float* xr = x2d + ((size_t)n * NN_ + m1 + wv * 16 + mmS) * 128 + oS * 8;
            #pragma unroll
            for (int kk = 0; kk < 4; ++kk) {
                float4 a = *(const float4*)&xr[kk * 32];
                float4 b = *(const float4*)&xr[kk * 32 + 4];
                f16x8_t f;
                f[0]=(_Float16)a.x; f[1]=(_Float16)a.y; f[2]=(_Float16)a.z; f[3]=(_Float16)a.w;
                f[4]=(_Float16)b.x; f[5]=(_Float16)b.y; f[6]=(_Float16)b.z; f[7]=(_Float16)b.w;
                afr[kk] = f;
            }
        }
        {
            const int mg = m0 + m3;
            const float* kb = kpackT4 + 4 * (size_t)mg;
            const float mko = 100000.0f * (1.0f - maskn * mask[mg]);
            #pragma unroll
            for (int e = 0; e < 3; ++e) {
                const int h = hg * 3 + e;
                float4 k0 = *(const float4*)&kb[(size_t)(h * 4 + 0) * 4096];
                float4 k1 = *(const float4*)&kb[(size_t)(h * 4 + 1) * 4096];
                float4 k2 = *(const float4*)&kb[(size_t)(h * 4 + 2) * 4096];
                float4 k3 = *(const float4*)&kb[(size_t)(h * 4 + 3) * 4096];
                float4 p0 = *(const float4*)&kb[(size_t)(48 + h) * 4096];
                float4 p1 = *(const float4*)&kb[(size_t)(60 + h) * 4096];
                float4 p2 = *(const float4*)&kb[(size_t)(72 + h) * 4096];
                float skm = skT[(size_t)h * 1024 + mg];
                const float4* qsn = (const float4*)&qs_l[h * 16];
                float dqs = qsn[0].x*k0.x + qsn[0].y*k0.y + qsn[0].z*k0.z + qsn[0].w*k0.w
                          + qsn[1].x*k1.x + qsn[1].y*k1.y + qsn[1].z*k1.z + qsn[1].w*k1.w
                          + qsn[2].x*k2.x + qsn[2].y*k2.y + qsn[2].z*k2.z + qsn[2].w*k2.w
                          + qsn[3].x*k3.x + qsn[3].y*k3.y + qsn[3].z*k3.z + qsn[3].w*k3.w;
                float4 qA = *(const float4*)&qp_l[h * 4];
                float4 qB = *(const float4*)&qp_l[48 + h * 4];
                float4 qC = *(const float4*)&qp_l[96 + h * 4];
                float qk = qA.x*p0.x + qA.y*p0.y + qA.z*p0.z + qA.w*p0.w
                         + qB.x*p1.x + qB.y*p1.y + qB.z*p1.z + qB.w*p1.w
                         + qC.x*p2.x + qC.y*p2.y + qC.z*p2.z + qC.w*p2.w;
                float pwh = pw_l[h];
                float lg = 0.14433756729740643f * dqs
                         + pwh * qk - 0.5f * pwh * (sq_l[h] + skm)
                         + 0.57735026918962576f * (at2_l[m3][h] + b2_l[h])
                         - mko;
                float tm = lg;
                tm = fmaxf(tm, __shfl_xor(tm, 1));
                tm = fmaxf(tm, __shfl_xor(tm, 2));
                tm = fmaxf(tm, __shfl_xor(tm, 4));
                tm = fmaxf(tm, __shfl_xor(tm, 8));
                tm = fmaxf(tm, __shfl_xor(tm, 16));
                tm = fmaxf(tm, __shfl_xor(tm, 32));
                float om = rmax_l[h];
                float nm = fmaxf(om, tm);
                float p = __expf(lg - nm);
                tlb[h][m3] = (_Float16)p;
                float ps = p;
                ps += __shfl_xor(ps, 1);
                ps += __shfl_xor(ps, 2);
                ps += __shfl_xor(ps, 4);
                ps += __shfl_xor(ps, 8);
                ps += __shfl_xor(ps, 16);
                ps += __shfl_xor(ps, 32);
                if (m3 == 0) {
                    float al = __expf(om - nm);
                    rmax_l[h] = nm;
                    alph_l[h] = al;
                    rsum_l[h] = rsum_l[h] * al + ps;
                }
            }
        }
        __syncthreads();   // (2) tlb / alph ready

        // ===== ACCUM: res2d + resF via MFMA =====
        {
            f32x4_t av = { alph_l[rowB], alph_l[rowB + 1], alph_l[rowB + 2], alph_l[rowB + 3] };
            accM[0] *= av;
            accM[1] *= av;
            #pragma unroll
            for (int jt = 0; jt < 8; ++jt) accF[jt] *= av;
            f16x8_t pA0 = *(const f16x8_t*)&tlb[ln & 15][(ln >> 4) * 8];
            f16x8_t pA1 = *(const f16x8_t*)&tlb[ln & 15][32 + (ln >> 4) * 8];
            #pragma unroll
            for (int nt = 0; nt < 2; ++nt) {
                int c = wv * 32 + nt * 16 + (ln & 15);
                f16x8_t xB0 = *(const f16x8_t*)&x_lT[c][(ln >> 4) * 8];
                f16x8_t xB1 = *(const f16x8_t*)&x_lT[c][32 + (ln >> 4) * 8];
                accM[nt] = __builtin_amdgcn_mfma_f32_16x16x32_f16(pA0, xB0, accM[nt], 0, 0, 0);
                accM[nt] = __builtin_amdgcn_mfma_f32_16x16x32_f16(pA1, xB1, accM[nt], 0, 0, 0);
            }
            const _Float16* vb = vT + (size_t)m0;
            #pragma unroll
            for (int jt = 0; jt < 8; ++jt) {
                int j = (wv * 8 + jt) * 16 + (ln & 15);
                f16x8_t vB0 = *(const f16x8_t*)&vb[(size_t)j * 1024 + (ln >> 4) * 8];
                f16x8_t vB1 = *(const f16x8_t*)&vb[(size_t)j * 1024 + 32 + (ln >> 4) * 8];
                accF[jt] = __builtin_amdgcn_mfma_f32_16x16x32_f16(pA0, vB0, accF[jt], 0, 0, 0);
                accF[jt] = __builtin_amdgcn_mfma_f32_16x16x32_f16(pA1, vB1, accF[jt], 0, 0, 0);
            }
        }
        __syncthreads();   // (3) protect x_lT / tlb / at2_l for next tile
    }

    // ================= epilogue =================
    #pragma unroll
    for (int nt = 0; nt < 2; ++nt) {
        #pragma unroll
        for (int r = 0; r < 4; ++r) {
            int row = rowB + r;
            if (row < 12) {
                int c = wv * 32 + nt * 16 + (ln & 15);
                fin[(size_t)n * DOUT_ + 576 + (size_t)row * 128 + c] = accM[nt][r] / rsum_l[row];
            }
        }
    }
    #pragma unroll
    for (int jt = 0; jt < 8; ++jt) {
        int j = (wv * 8 + jt) * 16 + (ln & 15);
        if (j < 480) {
            int hj = (j < 192) ? (j >> 4) : (((j - 192) % 96) >> 3);
            if (hj >= rowB && hj < rowB + 4) {
                float val = accF[jt][hj - rowB] / rsum_l[hj];
                if (j < 192) fin[(size_t)n * DOUT_ + j] = val;
                else         pg_l[j - 192] = val;
            }
        }
    }
    __syncthreads();
    if (t < 96) {
        const int k = t;
        float c0 = pg_l[k]       - rt_l[9];
        float c1 = pg_l[96 + k]  - rt_l[10];
        float c2 = pg_l[192 + k] - rt_l[11];
        float r0 = rt_l[0] * c0 + rt_l[3] * c1 + rt_l[6] * c2;
        float r1 = rt_l[1] * c0 + rt_l[4] * c1 + rt_l[7] * c2;
        float r2 = rt_l[2] * c0 + rt_l[5] * c1 + rt_l[8] * c2;
        size_t base = (size_t)n * DOUT_;
        fin[base + 192 + k] = r0;
        fin[base + 288 + k] = r1;
        fin[base + 384 + k] = r2;
        fin[base + 480 + k] = sqrtf(1e-8f + r0 * r0 + r1 * r1 + r2 * r2);
    }
}

// ---------------- K5: out partials, split-K over 4 chunks of 528 ----------------
__global__ __launch_bounds__(256) void k_out(
    const float* __restrict__ fin, const float* __restrict__ wo,
    float* __restrict__ pout)
{
    __shared__ float a_l[64 * 52];
    __shared__ float b_l[48 * 68];
    const int t = threadIdx.x;
    const int m0 = blockIdx.x * 64, n0 = blockIdx.y * 64, kc = blockIdx.z;
    const int tx = t & 15, ty = t >> 4;
    float acc[4][4] = {};
    for (int k0 = kc * 528; k0 < kc * 528 + 528; k0 += 48) {
        #pragma unroll
        for (int e = 0; e < 3; ++e) {
            int idx = t + 256 * e;
            int r = idx / 12, c4 = (idx % 12) * 4;
            *(float4*)&a_l[r * 52 + c4] = *(const float4*)&fin[(size_t)(m0 + r) * DOUT_ + k0 + c4];
        }
        #pragma unroll
        for (int e = 0; e < 3; ++e) {
            int idx = t + 256 * e;
            int r = idx >> 4, c4 = (idx & 15) * 4;
            *(float4*)&b_l[r * 68 + c4] = *(const float4*)&wo[(size_t)(k0 + r) * 384 + n0 + c4];
        }
        __syncthreads();
        #pragma unroll 4
        for (int k = 0; k < 48; ++k) {
            float4 bv = *(const float4*)&b_l[k * 68 + tx * 4];
            #pragma unroll
            for (int i = 0; i < 4; ++i) {
                float av = a_l[(ty * 4 + i) * 52 + k];
                acc[i][0] += av * bv.x; acc[i][1] += av * bv.y;
                acc[i][2] += av * bv.z; acc[i][3] += av * bv.w;
            }
        }
        __syncthreads();
    }
    float* pr = pout + (size_t)kc * 393216;
    #pragma unroll
    for (int i = 0; i < 4; ++i) {
        float4 o;
        o.x = acc[i][0]; o.y = acc[i][1]; o.z = acc[i][2]; o.w = acc[i][3];
        *(float4*)&pr[(size_t)(m0 + ty * 4 + i) * 384 + n0 + tx * 4] = o;
    }
}

// ---------------- K6: sum split-K partials + bias ----------------
__global__ __launch_bounds__(256) void k_fin(
    const float* __restrict__ pout, const float* __restrict__ bo, float* __restrict__ out)
{
    int idx = blockIdx.x * 256 + threadIdx.x;
    float4 a = *(const float4*)&pout[(size_t)idx * 4];
    float4 b = *(const float4*)&pout[393216 + (size_t)idx * 4];
    float4 c = *(const float4*)&pout[786432 + (size_t)idx * 4];
    float4 d = *(const float4*)&pout[1179648 + (size_t)idx * 4];
    float4 bias = *(const float4*)&bo[(idx % 96) * 4];
    float4 o;
    o.x = a.x + b.x + c.x + d.x + bias.x;
    o.y = a.y + b.y + c.y + d.y + bias.y;
    o.z = a.z + b.z + c.z + d.z + bias.z;
    o.w = a.w + b.w + c.w + d.w + bias.w;
    *(float4*)&out[(size_t)idx * 4] = o;
}

extern "C" void kernel_launch(void* const* d_in, const int* in_sizes, int n_in,
                              void* d_out, int out_size, void* d_ws, size_t ws_size,
                              hipStream_t stream) {
    const float* in1   = (const float*)d_in[0];
    const float* x2d   = (const float*)d_in[1];
    const float* mask  = (const float*)d_in[2];
    const float* rotm  = (const float*)d_in[3];
    const float* trans = (const float*)d_in[4];
    const float* wq    = (const float*)d_in[5];
    const float* bq    = (const float*)d_in[6];
    const float* wkv   = (const float*)d_in[7];
    const float* bkv   = (const float*)d_in[8];
    const float* wqp   = (const float*)d_in[9];
    const float* bqp   = (const float*)d_in[10];
    const float* wkvp  = (const float*)d_in[11];
    const float* bkvp  = (const float*)d_in[12];
    const float* w2d   = (const float*)d_in[13];
    const float* b2d   = (const float*)d_in[14];
    const float* tpw   = (const float*)d_in[15];
    const float* wo    = (const float*)d_in[16];
    const float* bo    = (const float*)d_in[17];
    float* out = (float*)d_out;

    float* ws = (float*)d_ws;
    float* yraw    = ws;                    // 1,179,648
    float* qp_arr  = yraw + 1179648;        //   147,456
    float* kpackT4 = qp_arr + 147456;       //   360,448
    float* vT_f    = kpackT4 + 360448;      //   262,144 (512 x 1024 fp16)
    float* sq_arr  = vT_f + 262144;         //    12,288
    float* fin     = sq_arr + 12288;        // 2,162,688
    float* pout    = fin + 2162688;         // 1,572,864
    float* skT     = pout + 1572864;        //    12,288
    _Float16* vT = (_Float16*)vT_f;

    hipLaunchKernelGGL(k_gemm1, dim3(16, 18), dim3(256), 0, stream,
        in1, wq, bq, wkv, bkv, wqp, bqp, wkvp, bkvp, yraw);
    hipLaunchKernelGGL(k_rot, dim3(256), dim3(256), 0, stream,
        yraw, rotm, trans, qp_arr, kpackT4, vT, sq_arr, skT);
    hipLaunchKernelGGL(k_attn9, dim3(1024), dim3(256), 0, stream,
        x2d, mask, w2d, b2d, tpw, yraw, qp_arr, kpackT4, vT, sq_arr, skT, rotm, trans, fin);
    hipLaunchKernelGGL(k_out, dim3(16, 6, 4), dim3(256), 0, stream, fin, wo, pout);
    hipLaunchKernelGGL(k_fin, dim3(384), dim3(256), 0, stream, pout, bo, out);
}